// Round 3
// baseline (581.469 us; speedup 1.0000x reference)
//
#include <hip/hip_runtime.h>

typedef __bf16 bf16;
typedef __bf16 bf16x4 __attribute__((ext_vector_type(4)));
typedef __bf16 bf16x8 __attribute__((ext_vector_type(8)));
typedef float f32x4 __attribute__((ext_vector_type(4)));
typedef float f32x16 __attribute__((ext_vector_type(16)));

#define NB 2
#define SEQ 4096
#define HID 768
#define NHEAD 12
#define HDIM 64
#define MTOT (NB * SEQ)   // 8192
#define LOG2E 1.4426950408889634f

// ---------------- fp32 -> bf16 convert (vectorized) ----------------
__global__ __launch_bounds__(256) void cvt_kernel(const float* __restrict__ in,
                                                  bf16* __restrict__ out, int n4) {
    int stride = gridDim.x * blockDim.x;
    for (int i = blockIdx.x * blockDim.x + threadIdx.x; i < n4; i += stride) {
        float4 v = reinterpret_cast<const float4*>(in)[i];
        bf16x4 o;
        o[0] = (bf16)v.x; o[1] = (bf16)v.y; o[2] = (bf16)v.z; o[3] = (bf16)v.w;
        reinterpret_cast<bf16x4*>(out)[i] = o;
    }
}

// ---------------- fused QKV projection GEMM ----------------
__global__ __launch_bounds__(256) void qkv_gemm(
    const bf16* __restrict__ Xb,
    const bf16* __restrict__ Wq, const bf16* __restrict__ Wk, const bf16* __restrict__ Wv,
    const float* __restrict__ bq, const float* __restrict__ bk, const float* __restrict__ bv,
    bf16* __restrict__ Qh, bf16* __restrict__ Kh, bf16* __restrict__ Vt)
{
    int z = blockIdx.z;
    const bf16* W = (z == 0) ? Wq : (z == 1) ? Wk : Wv;
    const float* bias = (z == 0) ? bq : (z == 1) ? bk : bv;

    int lane = threadIdx.x & 63;
    int wid  = threadIdx.x >> 6;
    int wm = wid >> 1, wn = wid & 1;
    int g = lane >> 4, c = lane & 15;
    int m0 = blockIdx.y * 128 + wm * 64;
    int n0 = blockIdx.x * 128 + wn * 64;

    f32x4 acc[4][4] = {};
    const bf16* Aptr = Xb + (size_t)(m0 + c) * HID + g * 8;
    const bf16* Bptr = W  + (size_t)(n0 + c) * HID + g * 8;

    for (int k0 = 0; k0 < HID; k0 += 32) {
        bf16x8 a[4], b[4];
#pragma unroll
        for (int i = 0; i < 4; i++) {
            a[i] = *reinterpret_cast<const bf16x8*>(Aptr + (size_t)i * 16 * HID + k0);
            b[i] = *reinterpret_cast<const bf16x8*>(Bptr + (size_t)i * 16 * HID + k0);
        }
#pragma unroll
        for (int mi = 0; mi < 4; mi++)
#pragma unroll
            for (int ni = 0; ni < 4; ni++)
                acc[mi][ni] = __builtin_amdgcn_mfma_f32_16x16x32_bf16(a[mi], b[ni], acc[mi][ni], 0, 0, 0);
    }

#pragma unroll
    for (int ni = 0; ni < 4; ni++) {
        int n = n0 + ni * 16 + c;
        float bval = bias[n];
        int h = n >> 6, d = n & 63;
#pragma unroll
        for (int mi = 0; mi < 4; mi++) {
#pragma unroll
            for (int j = 0; j < 4; j++) {
                int m = m0 + mi * 16 + g * 4 + j;
                float val = acc[mi][ni][j] + bval;
                int bb = m >> 12, s = m & 4095;
                if (z == 0) {
                    // pre-scale Q by 1/sqrt(HD) * log2(e) for exp2-domain softmax
                    val *= 0.125f * LOG2E;
                    Qh[((size_t)(bb * NHEAD + h) * SEQ + s) * HDIM + d] = (bf16)val;
                } else if (z == 1) {
                    Kh[((size_t)(bb * NHEAD + h) * SEQ + s) * HDIM + d] = (bf16)val;
                } else {
                    Vt[((size_t)(bb * NHEAD + h) * HDIM + d) * SEQ + s] = (bf16)val;
                }
            }
        }
    }
}

// ---------------- flash attention (barrier-free, direct-from-L2) ----------------
// grid: (NB*NHEAD, SEQ/32); 64 threads = 1 independent wave owning 32 q-rows.
// XCD = (bh + 24*qb) % 8 = bh % 8  -> each XCD touches 3 heads (3MB K/V, L2-fits).
// S = K*Q^T -> D[k][q], col=q=lane&31: softmax state per-lane scalar.
// O^T = V^T*P^T -> D[d][q]: rescale per-lane broadcast.
__global__ __launch_bounds__(64) void attn_kernel(
    const bf16* __restrict__ Qh, const bf16* __restrict__ Kh, const bf16* __restrict__ Vt,
    const float* __restrict__ mask, bf16* __restrict__ ctx)
{
    __shared__ bf16 Ep[2048];          // 4KB per-wave epilogue coalesce buffer

    const int lane = threadIdx.x;      // 0..63
    const int lq = lane & 31;
    const int hi = lane >> 5;
    const int bh = blockIdx.x;
    const int b = bh / NHEAD, h = bh % NHEAD;
    const size_t base = (size_t)bh * SEQ * HDIM;
    const int qw = blockIdx.y * 32;

    // Q B-frags (pre-scaled by 0.125*log2e): lane holds Q[qw+lq][dc*16+hi*8+j]
    bf16x8 qf[4];
    {
        const bf16* qp = Qh + base + (size_t)(qw + lq) * HDIM + hi * 8;
#pragma unroll
        for (int dc = 0; dc < 4; dc++)
            qf[dc] = *reinterpret_cast<const bf16x8*>(qp + dc * 16);
    }
    const float* maskb = mask + b * SEQ;

    // fragment base pointers (direct global reads, L1/L2-resident tiles)
    const bf16* kp0 = Kh + base + (size_t)lq * HDIM + hi * 8;
    const bf16* vp0 = Vt + base + (size_t)lq * SEQ + hi * 8;

    float m_r = -3e38f, l_r = 0.f;
    f32x16 o0 = {}, o1 = {};

    const int NT = SEQ / 64;
    for (int kt = 0; kt < NT; kt++) {
        // ---- issue all 16 fragment loads up front (no LDS, no barriers) ----
        const bf16* kb_ = kp0 + (size_t)kt * 64 * HDIM;
        const bf16* vb_ = vp0 + (size_t)kt * 64;
        bf16x8 ka[4], kc2[4], va[4], vc2[4];
#pragma unroll
        for (int dc = 0; dc < 4; dc++) {
            ka[dc]  = *reinterpret_cast<const bf16x8*>(kb_ + dc * 16);
            kc2[dc] = *reinterpret_cast<const bf16x8*>(kb_ + 32 * HDIM + dc * 16);
        }
#pragma unroll
        for (int kc = 0; kc < 4; kc++) {
            va[kc]  = *reinterpret_cast<const bf16x8*>(vb_ + kc * 16);
            vc2[kc] = *reinterpret_cast<const bf16x8*>(vb_ + (size_t)32 * SEQ + kc * 16);
        }

        // ---- QK^T: S[k][q], rows 0-31 (s0) and 32-63 (s1) ----
        f32x16 s0 = {}, s1 = {};
#pragma unroll
        for (int dc = 0; dc < 4; dc++) {
            s0 = __builtin_amdgcn_mfma_f32_32x32x16_bf16(ka[dc],  qf[dc], s0, 0, 0, 0);
            s1 = __builtin_amdgcn_mfma_f32_32x32x16_bf16(kc2[dc], qf[dc], s1, 0, 0, 0);
        }

        // ---- mask add (exp2 domain) + tree max ----
        const float* mrow = maskb + kt * 64 + hi * 4;
#pragma unroll
        for (int ks = 0; ks < 2; ks++) {
            f32x16& sc = ks ? s1 : s0;
#pragma unroll
            for (int g4 = 0; g4 < 4; g4++) {
                f32x4 mk = *(const f32x4*)(mrow + ks * 32 + g4 * 8);
#pragma unroll
                for (int j = 0; j < 4; j++)
                    sc[g4 * 4 + j] += mk[j] * LOG2E;
            }
        }
        float r[16];
#pragma unroll
        for (int i = 0; i < 16; i++) r[i] = fmaxf(s0[i], s1[i]);
#pragma unroll
        for (int st = 8; st > 0; st >>= 1)
#pragma unroll
            for (int i = 0; i < st; i++) r[i] = fmaxf(r[i], r[i + st]);
        float tmax = fmaxf(r[0], __shfl_xor(r[0], 32));

        if (__any(tmax > m_r + 8.f)) {         // defer-max (T13)
            float mnew = fmaxf(m_r, tmax);
            float alpha = __builtin_amdgcn_exp2f(m_r - mnew);
            m_r = mnew;
            l_r *= alpha;
#pragma unroll
            for (int i = 0; i < 16; i++) { o0[i] *= alpha; o1[i] *= alpha; }
        }

        // ---- exp2 + tree sum ----
#pragma unroll
        for (int i = 0; i < 16; i++) {
            s0[i] = __builtin_amdgcn_exp2f(s0[i] - m_r);
            s1[i] = __builtin_amdgcn_exp2f(s1[i] - m_r);
        }
#pragma unroll
        for (int i = 0; i < 16; i++) r[i] = s0[i] + s1[i];
#pragma unroll
        for (int st = 8; st > 0; st >>= 1)
#pragma unroll
            for (int i = 0; i < st; i++) r[i] += r[i + st];
        l_r += r[0] + __shfl_xor(r[0], 32);

        // ---- P (f32 D-layout) -> bf16 B-frags via cvt + permlane32_swap ----
        bf16x8 pa[4];
#pragma unroll
        for (int ks = 0; ks < 2; ks++) {
            f32x16& sc = ks ? s1 : s0;
            unsigned u[8];
#pragma unroll
            for (int i = 0; i < 8; i++) {
                union { bf16 hh[2]; unsigned uu; } x;
                x.hh[0] = (bf16)sc[i * 2];
                x.hh[1] = (bf16)sc[i * 2 + 1];
                u[i] = x.uu;
            }
            asm("v_permlane32_swap_b32 %0, %1" : "+v"(u[0]), "+v"(u[2]));
            asm("v_permlane32_swap_b32 %0, %1" : "+v"(u[1]), "+v"(u[3]));
            asm("v_permlane32_swap_b32 %0, %1" : "+v"(u[4]), "+v"(u[6]));
            asm("v_permlane32_swap_b32 %0, %1" : "+v"(u[5]), "+v"(u[7]));
            union { unsigned uu[4]; bf16x8 v; } f0, f1;
            f0.uu[0] = u[0]; f0.uu[1] = u[1]; f0.uu[2] = u[2]; f0.uu[3] = u[3];
            f1.uu[0] = u[4]; f1.uu[1] = u[5]; f1.uu[2] = u[6]; f1.uu[3] = u[7];
            pa[ks * 2]     = f0.v;
            pa[ks * 2 + 1] = f1.v;
        }

        // ---- PV: O^T[d][q] += V^T * P^T ----
#pragma unroll
        for (int kc = 0; kc < 4; kc++) {
            o0 = __builtin_amdgcn_mfma_f32_32x32x16_bf16(va[kc],  pa[kc], o0, 0, 0, 0);
            o1 = __builtin_amdgcn_mfma_f32_32x32x16_bf16(vc2[kc], pa[kc], o1, 0, 0, 0);
        }
    }

    // ---- epilogue: O/l -> LDS (same-wave coalesce) -> global ----
    float invl = 1.f / l_r;
    const int swr = (lq & 7) << 4;
#pragma unroll
    for (int dn = 0; dn < 2; dn++) {
        f32x16& oo = dn ? o1 : o0;
#pragma unroll
        for (int g4 = 0; g4 < 4; g4++) {
            bf16x4 pk4;
#pragma unroll
            for (int j = 0; j < 4; j++) pk4[j] = (bf16)(oo[g4 * 4 + j] * invl);
            int colb = (dn * 64 + g4 * 16 + hi * 8) ^ swr;
            *(bf16x4*)((char*)Ep + lq * 128 + colb) = pk4;
        }
    }
    const int r8 = lane >> 3;
    const int c8 = lane & 7;
#pragma unroll
    for (int cc = 0; cc < 4; cc++) {
        int row = cc * 8 + r8;
        int colb = (c8 * 16) ^ (r8 << 4);
        bf16x8 val = *(const bf16x8*)((const char*)Ep + row * 128 + colb);
        *(bf16x8*)(ctx + (size_t)(b * SEQ + qw + row) * HID + h * 64 + c8 * 8) = val;
    }
}

// ---------------- output projection + bias + residual ----------------
__global__ __launch_bounds__(256) void oproj_gemm(
    const bf16* __restrict__ Cb, const bf16* __restrict__ Wo, const float* __restrict__ bo,
    const float* __restrict__ hidden, float* __restrict__ y)
{
    int lane = threadIdx.x & 63;
    int wid  = threadIdx.x >> 6;
    int wm = wid >> 1, wn = wid & 1;
    int g = lane >> 4, c = lane & 15;
    int m0 = blockIdx.y * 128 + wm * 64;
    int n0 = blockIdx.x * 128 + wn * 64;

    f32x4 acc[4][4] = {};
    const bf16* Aptr = Cb + (size_t)(m0 + c) * HID + g * 8;
    const bf16* Bptr = Wo + (size_t)(n0 + c) * HID + g * 8;

    for (int k0 = 0; k0 < HID; k0 += 32) {
        bf16x8 a[4], b[4];
#pragma unroll
        for (int i = 0; i < 4; i++) {
            a[i] = *reinterpret_cast<const bf16x8*>(Aptr + (size_t)i * 16 * HID + k0);
            b[i] = *reinterpret_cast<const bf16x8*>(Bptr + (size_t)i * 16 * HID + k0);
        }
#pragma unroll
        for (int mi = 0; mi < 4; mi++)
#pragma unroll
            for (int ni = 0; ni < 4; ni++)
                acc[mi][ni] = __builtin_amdgcn_mfma_f32_16x16x32_bf16(a[mi], b[ni], acc[mi][ni], 0, 0, 0);
    }

#pragma unroll
    for (int ni = 0; ni < 4; ni++) {
        int n = n0 + ni * 16 + c;
        float bval = bo[n];
#pragma unroll
        for (int mi = 0; mi < 4; mi++) {
#pragma unroll
            for (int j = 0; j < 4; j++) {
                int m = m0 + mi * 16 + g * 4 + j;
                size_t idx = (size_t)m * HID + n;
                y[idx] = acc[mi][ni][j] + bval + hidden[idx];
            }
        }
    }
}

// ---------------- LayerNorm ----------------
__global__ __launch_bounds__(256) void ln_kernel(
    const float* __restrict__ y, const float* __restrict__ gam,
    const float* __restrict__ bet, float* __restrict__ out)
{
    int row = blockIdx.x * 4 + (threadIdx.x >> 6);
    int lane = threadIdx.x & 63;
    const float* yr = y + (size_t)row * HID;

    float4 v[3];
#pragma unroll
    for (int i = 0; i < 3; i++)
        v[i] = reinterpret_cast<const float4*>(yr)[lane + i * 64];

    float s = 0.f;
#pragma unroll
    for (int i = 0; i < 3; i++) s += v[i].x + v[i].y + v[i].z + v[i].w;
#pragma unroll
    for (int msk = 1; msk < 64; msk <<= 1) s += __shfl_xor(s, msk, 64);
    float mean = s * (1.f / 768.f);

    float q = 0.f;
#pragma unroll
    for (int i = 0; i < 3; i++) {
        float dx = v[i].x - mean, dy = v[i].y - mean, dz = v[i].z - mean, dw = v[i].w - mean;
        q += dx * dx + dy * dy + dz * dz + dw * dw;
    }
#pragma unroll
    for (int msk = 1; msk < 64; msk <<= 1) q += __shfl_xor(q, msk, 64);
    float rstd = rsqrtf(q * (1.f / 768.f) + 1e-12f);

    float* outr = out + (size_t)row * HID;
#pragma unroll
    for (int i = 0; i < 3; i++) {
        float4 gg = reinterpret_cast<const float4*>(gam)[lane + i * 64];
        float4 bb = reinterpret_cast<const float4*>(bet)[lane + i * 64];
        float4 o;
        o.x = (v[i].x - mean) * rstd * gg.x + bb.x;
        o.y = (v[i].y - mean) * rstd * gg.y + bb.y;
        o.z = (v[i].z - mean) * rstd * gg.z + bb.z;
        o.w = (v[i].w - mean) * rstd * gg.w + bb.w;
        reinterpret_cast<float4*>(outr)[lane + i * 64] = o;
    }
}

extern "C" void kernel_launch(void* const* d_in, const int* in_sizes, int n_in,
                              void* d_out, int out_size, void* d_ws, size_t ws_size,
                              hipStream_t stream) {
    const float* hidden = (const float*)d_in[0];
    const float* mask   = (const float*)d_in[1];
    const float* q_w = (const float*)d_in[2];
    const float* q_b = (const float*)d_in[3];
    const float* k_w = (const float*)d_in[4];
    const float* k_b = (const float*)d_in[5];
    const float* v_w = (const float*)d_in[6];
    const float* v_b = (const float*)d_in[7];
    const float* o_w = (const float*)d_in[8];
    const float* o_b = (const float*)d_in[9];
    const float* ln_g = (const float*)d_in[10];
    const float* ln_b = (const float*)d_in[11];
    float* out = (float*)d_out;

    const size_t SZ_X = (size_t)MTOT * HID;
    const size_t SZ_W = (size_t)HID * HID;

    char* ws = (char*)d_ws;
    size_t XB_OFF = 0;
    size_t W_OFF  = XB_OFF + SZ_X * 2;
    size_t QH_OFF = W_OFF + 4 * SZ_W * 2;
    size_t KH_OFF = QH_OFF + SZ_X * 2;
    size_t VT_OFF = KH_OFF + SZ_X * 2;

    bf16* Xb  = (bf16*)(ws + XB_OFF);
    bf16* Wqb = (bf16*)(ws + W_OFF);
    bf16* Wkb = Wqb + SZ_W;
    bf16* Wvb = Wkb + SZ_W;
    bf16* Wob = Wvb + SZ_W;
    bf16* Qh  = (bf16*)(ws + QH_OFF);
    bf16* Kh  = (bf16*)(ws + KH_OFF);
    bf16* Vt  = (bf16*)(ws + VT_OFF);
    bf16* ctx = (bf16*)(ws + XB_OFF);
    float* y  = (float*)(ws + QH_OFF);

    cvt_kernel<<<dim3((SZ_X / 4 + 255) / 256), 256, 0, stream>>>(hidden, Xb, SZ_X / 4);
    cvt_kernel<<<dim3((SZ_W / 4 + 255) / 256), 256, 0, stream>>>(q_w, Wqb, SZ_W / 4);
    cvt_kernel<<<dim3((SZ_W / 4 + 255) / 256), 256, 0, stream>>>(k_w, Wkb, SZ_W / 4);
    cvt_kernel<<<dim3((SZ_W / 4 + 255) / 256), 256, 0, stream>>>(v_w, Wvb, SZ_W / 4);
    cvt_kernel<<<dim3((SZ_W / 4 + 255) / 256), 256, 0, stream>>>(o_w, Wob, SZ_W / 4);

    qkv_gemm<<<dim3(HID / 128, MTOT / 128, 3), 256, 0, stream>>>(
        Xb, Wqb, Wkb, Wvb, q_b, k_b, v_b, Qh, Kh, Vt);

    // barrier-free attention: 1 wave per block, XCD = bh%8 pins heads to XCDs
    attn_kernel<<<dim3(NB * NHEAD, SEQ / 32), 64, 0, stream>>>(Qh, Kh, Vt, mask, ctx);

    oproj_gemm<<<dim3(HID / 128, MTOT / 128), 256, 0, stream>>>(ctx, Wob, o_b, hidden, y);

    ln_kernel<<<dim3(MTOT / 4), 256, 0, stream>>>(y, ln_g, ln_b, out);
}

// Round 4
// 502.221 us; speedup vs baseline: 1.1578x; 1.1578x over previous
//
#include <hip/hip_runtime.h>

typedef __bf16 bf16;
typedef __bf16 bf16x4 __attribute__((ext_vector_type(4)));
typedef __bf16 bf16x8 __attribute__((ext_vector_type(8)));
typedef float f32x4 __attribute__((ext_vector_type(4)));
typedef float f32x16 __attribute__((ext_vector_type(16)));

#define NB 2
#define SEQ 4096
#define HID 768
#define NHEAD 12
#define HDIM 64
#define MTOT (NB * SEQ)   // 8192
#define LOG2E 1.4426950408889634f

// ---------------- fp32 -> bf16 convert (vectorized) ----------------
__global__ __launch_bounds__(256) void cvt_kernel(const float* __restrict__ in,
                                                  bf16* __restrict__ out, int n4) {
    int stride = gridDim.x * blockDim.x;
    for (int i = blockIdx.x * blockDim.x + threadIdx.x; i < n4; i += stride) {
        float4 v = reinterpret_cast<const float4*>(in)[i];
        bf16x4 o;
        o[0] = (bf16)v.x; o[1] = (bf16)v.y; o[2] = (bf16)v.z; o[3] = (bf16)v.w;
        reinterpret_cast<bf16x4*>(out)[i] = o;
    }
}

// ---------------- fused QKV projection GEMM ----------------
// K and V are written FRAGMENT-PACKED per (bh, 64-row tile):
//   tile = 8 fragments x 64 lanes x 8 bf16 (4096 elems = 8KB).
// K frag f=khalf*4+dc, lane holds K[kt*64+khalf*32+(lane&31)][dc*16+(lane>>5)*8+j]
// V frag f=dhalf*4+kc, lane holds V[kt*64+kc*16+(lane>>5)*8+j][dhalf*32+(lane&31)]
__global__ __launch_bounds__(256) void qkv_gemm(
    const bf16* __restrict__ Xb,
    const bf16* __restrict__ Wq, const bf16* __restrict__ Wk, const bf16* __restrict__ Wv,
    const float* __restrict__ bq, const float* __restrict__ bk, const float* __restrict__ bv,
    bf16* __restrict__ Qh, bf16* __restrict__ Kh, bf16* __restrict__ Vt)
{
    int z = blockIdx.z;
    const bf16* W = (z == 0) ? Wq : (z == 1) ? Wk : Wv;
    const float* bias = (z == 0) ? bq : (z == 1) ? bk : bv;

    int lane = threadIdx.x & 63;
    int wid  = threadIdx.x >> 6;
    int wm = wid >> 1, wn = wid & 1;
    int g = lane >> 4, c = lane & 15;
    int m0 = blockIdx.y * 128 + wm * 64;
    int n0 = blockIdx.x * 128 + wn * 64;

    f32x4 acc[4][4] = {};
    const bf16* Aptr = Xb + (size_t)(m0 + c) * HID + g * 8;
    const bf16* Bptr = W  + (size_t)(n0 + c) * HID + g * 8;

    for (int k0 = 0; k0 < HID; k0 += 32) {
        bf16x8 a[4], b[4];
#pragma unroll
        for (int i = 0; i < 4; i++) {
            a[i] = *reinterpret_cast<const bf16x8*>(Aptr + (size_t)i * 16 * HID + k0);
            b[i] = *reinterpret_cast<const bf16x8*>(Bptr + (size_t)i * 16 * HID + k0);
        }
#pragma unroll
        for (int mi = 0; mi < 4; mi++)
#pragma unroll
            for (int ni = 0; ni < 4; ni++)
                acc[mi][ni] = __builtin_amdgcn_mfma_f32_16x16x32_bf16(a[mi], b[ni], acc[mi][ni], 0, 0, 0);
    }

#pragma unroll
    for (int ni = 0; ni < 4; ni++) {
        int n = n0 + ni * 16 + c;
        float bval = bias[n];
        int h = n >> 6, d = n & 63;
#pragma unroll
        for (int mi = 0; mi < 4; mi++) {
#pragma unroll
            for (int j = 0; j < 4; j++) {
                int m = m0 + mi * 16 + g * 4 + j;
                float val = acc[mi][ni][j] + bval;
                int bb = m >> 12, s = m & 4095;
                size_t bhb = (size_t)(bb * NHEAD + h) * SEQ * HDIM;
                if (z == 0) {
                    // pre-scale Q by 1/sqrt(HD) * log2(e) for exp2-domain softmax
                    val *= 0.125f * LOG2E;
                    Qh[bhb + (size_t)s * HDIM + d] = (bf16)val;
                } else if (z == 1) {
                    int fragidx = (((s >> 5) & 1) << 2) | (d >> 4);
                    int lane2 = (s & 31) | (((d >> 3) & 1) << 5);
                    Kh[bhb + (size_t)(s >> 6) * 4096 + fragidx * 512 + lane2 * 8 + (d & 7)] = (bf16)val;
                } else {
                    int fragidx = ((d >> 5) << 2) | ((s >> 4) & 3);
                    int lane2 = (d & 31) | (((s >> 3) & 1) << 5);
                    Vt[bhb + (size_t)(s >> 6) * 4096 + fragidx * 512 + lane2 * 8 + (s & 7)] = (bf16)val;
                }
            }
        }
    }
}

// ---------------- softmax helpers ----------------
__device__ inline void smax_update(f32x16& sA, f32x16& sB, float& m, float& l,
                                   f32x16& oA, f32x16& oB) {
    float r[16];
#pragma unroll
    for (int i = 0; i < 16; i++) r[i] = fmaxf(sA[i], sB[i]);
#pragma unroll
    for (int st = 8; st; st >>= 1)
#pragma unroll
        for (int i = 0; i < st; i++) r[i] = fmaxf(r[i], r[i + st]);
    float t = fmaxf(r[0], __shfl_xor(r[0], 32));
    if (__any(t > m + 8.f)) {          // defer-max (T13)
        float mn = fmaxf(m, t);
        float al = __builtin_amdgcn_exp2f(m - mn);
        m = mn; l *= al;
#pragma unroll
        for (int i = 0; i < 16; i++) { oA[i] *= al; oB[i] *= al; }
    }
#pragma unroll
    for (int i = 0; i < 16; i++) {
        sA[i] = __builtin_amdgcn_exp2f(sA[i] - m);
        sB[i] = __builtin_amdgcn_exp2f(sB[i] - m);
    }
    float q[16];
#pragma unroll
    for (int i = 0; i < 16; i++) q[i] = sA[i] + sB[i];
#pragma unroll
    for (int st = 8; st; st >>= 1)
#pragma unroll
        for (int i = 0; i < st; i++) q[i] += q[i + st];
    l += q[0] + __shfl_xor(q[0], 32);
}

// P (f32 D-layout, khalf pair) -> 4 bf16 B-frags via cvt_pk + permlane32_swap
__device__ inline void pconv(f32x16& sA, f32x16& sB, bf16x8* pa) {
#pragma unroll
    for (int ks = 0; ks < 2; ks++) {
        f32x16& sc = ks ? sB : sA;
        unsigned u[8];
#pragma unroll
        for (int i = 0; i < 8; i++) {
            union { bf16 hh[2]; unsigned uu; } x;
            x.hh[0] = (bf16)sc[i * 2];
            x.hh[1] = (bf16)sc[i * 2 + 1];
            u[i] = x.uu;
        }
        asm("v_permlane32_swap_b32 %0, %1" : "+v"(u[0]), "+v"(u[2]));
        asm("v_permlane32_swap_b32 %0, %1" : "+v"(u[1]), "+v"(u[3]));
        asm("v_permlane32_swap_b32 %0, %1" : "+v"(u[4]), "+v"(u[6]));
        asm("v_permlane32_swap_b32 %0, %1" : "+v"(u[5]), "+v"(u[7]));
        union { unsigned uu[4]; bf16x8 v; } f0, f1;
        f0.uu[0] = u[0]; f0.uu[1] = u[1]; f0.uu[2] = u[2]; f0.uu[3] = u[3];
        f1.uu[0] = u[4]; f1.uu[1] = u[5]; f1.uu[2] = u[6]; f1.uu[3] = u[7];
        pa[ks * 2]     = f0.v;
        pa[ks * 2 + 1] = f1.v;
    }
}

// ---------------- flash attention (barrier-free, fragment-packed K/V) ----------------
// grid: (NB*NHEAD, SEQ/64); 64 threads = 1 independent wave owning 64 q-rows.
// XCD = blockid%8 = bh%8 -> 3 heads per XCD (3MB K/V, L2-resident).
// All K/V loads are lane-contiguous 16B (1KB/instruction) thanks to frag-packing.
__global__ __launch_bounds__(64) void attn_kernel(
    const bf16* __restrict__ Qh, const bf16* __restrict__ Kh, const bf16* __restrict__ Vt,
    const float* __restrict__ mask, bf16* __restrict__ ctx)
{
    __shared__ bf16 Ep[4096];          // 8KB epilogue coalesce buffer (64 rows x 128B)

    const int lane = threadIdx.x;      // 0..63
    const int lq = lane & 31;
    const int hi = lane >> 5;
    const int bh = blockIdx.x;
    const int b = bh / NHEAD, h = bh % NHEAD;
    const size_t base = (size_t)bh * SEQ * HDIM;
    const int qw = blockIdx.y * 64;

    // Q B-frags (pre-scaled): qf{0,1}[dc] -> lane holds Q[qw+qh*32+lq][dc*16+hi*8+j]
    bf16x8 qf0[4], qf1[4];
#pragma unroll
    for (int dc = 0; dc < 4; dc++) {
        qf0[dc] = *(const bf16x8*)(Qh + base + (size_t)(qw + lq) * HDIM + dc * 16 + hi * 8);
        qf1[dc] = *(const bf16x8*)(Qh + base + (size_t)(qw + 32 + lq) * HDIM + dc * 16 + hi * 8);
    }
    const float* maskb = mask + b * SEQ;

    const bf16* kfrag = Kh + base + (size_t)lane * 8;
    const bf16* vfrag = Vt + base + (size_t)lane * 8;

    float m0 = -3e38f, m1 = -3e38f, l0 = 0.f, l1 = 0.f;
    f32x16 o00 = {}, o01 = {}, o10 = {}, o11 = {};   // o[qhalf][dhalf]

    for (int kt = 0; kt < SEQ / 64; kt++) {
        const bf16* kb_ = kfrag + (size_t)kt * 4096;
        const bf16* vb_ = vfrag + (size_t)kt * 4096;
        bf16x8 kf[8], vf[8];
#pragma unroll
        for (int f = 0; f < 8; f++) kf[f] = *(const bf16x8*)(kb_ + f * 512);
#pragma unroll
        for (int f = 0; f < 8; f++) vf[f] = *(const bf16x8*)(vb_ + f * 512);

        // ---- QK^T: s[qhalf][khalf] = K * Q^T, D[k][q] ----
        f32x16 s00 = {}, s01 = {}, s10 = {}, s11 = {};
#pragma unroll
        for (int dc = 0; dc < 4; dc++) {
            s00 = __builtin_amdgcn_mfma_f32_32x32x16_bf16(kf[dc],     qf0[dc], s00, 0, 0, 0);
            s01 = __builtin_amdgcn_mfma_f32_32x32x16_bf16(kf[4 + dc], qf0[dc], s01, 0, 0, 0);
            s10 = __builtin_amdgcn_mfma_f32_32x32x16_bf16(kf[dc],     qf1[dc], s10, 0, 0, 0);
            s11 = __builtin_amdgcn_mfma_f32_32x32x16_bf16(kf[4 + dc], qf1[dc], s11, 0, 0, 0);
        }

        // ---- mask add (exp2 domain), shared across qhalves ----
        const float* mrow = maskb + kt * 64 + hi * 4;
#pragma unroll
        for (int ks = 0; ks < 2; ks++) {
#pragma unroll
            for (int g = 0; g < 4; g++) {
                f32x4 mk = *(const f32x4*)(mrow + ks * 32 + g * 8);
#pragma unroll
                for (int j = 0; j < 4; j++) {
                    float mval = mk[j] * LOG2E;
                    if (ks == 0) { s00[g * 4 + j] += mval; s10[g * 4 + j] += mval; }
                    else         { s01[g * 4 + j] += mval; s11[g * 4 + j] += mval; }
                }
            }
        }

        // ---- softmax + P conversion, qhalf 0 then 1 (limits register liveness) ----
        bf16x8 pa0[4], pa1[4];
        smax_update(s00, s01, m0, l0, o00, o01);
        pconv(s00, s01, pa0);
        smax_update(s10, s11, m1, l1, o10, o11);
        pconv(s10, s11, pa1);

        // ---- PV: o[qhalf][dhalf] += V^T * P^T ----
#pragma unroll
        for (int kc = 0; kc < 4; kc++) {
            o00 = __builtin_amdgcn_mfma_f32_32x32x16_bf16(vf[kc],     pa0[kc], o00, 0, 0, 0);
            o01 = __builtin_amdgcn_mfma_f32_32x32x16_bf16(vf[4 + kc], pa0[kc], o01, 0, 0, 0);
            o10 = __builtin_amdgcn_mfma_f32_32x32x16_bf16(vf[kc],     pa1[kc], o10, 0, 0, 0);
            o11 = __builtin_amdgcn_mfma_f32_32x32x16_bf16(vf[4 + kc], pa1[kc], o11, 0, 0, 0);
        }
    }

    // ---- epilogue: O/l -> LDS (same-wave coalesce, swizzled) -> global ----
    float inv0 = 1.f / l0, inv1 = 1.f / l1;
#pragma unroll
    for (int qh = 0; qh < 2; qh++) {
        f32x16& a = qh ? o10 : o00;
        f32x16& bq_ = qh ? o11 : o01;
        float inv = qh ? inv1 : inv0;
        int q = qh * 32 + lq;
        int sw = (q & 7) << 4;
#pragma unroll
        for (int g = 0; g < 4; g++) {
            bf16x4 p0, p1;
#pragma unroll
            for (int j = 0; j < 4; j++) {
                p0[j] = (bf16)(a[g * 4 + j] * inv);
                p1[j] = (bf16)(bq_[g * 4 + j] * inv);
            }
            int colb = g * 16 + hi * 8;
            *(bf16x4*)((char*)Ep + q * 128 + (colb ^ sw)) = p0;
            *(bf16x4*)((char*)Ep + q * 128 + ((64 + colb) ^ sw)) = p1;
        }
    }
    // single wave: compiler inserts lgkmcnt between ds_write and ds_read
    const int r8 = lane >> 3;
    const int c8 = lane & 7;
#pragma unroll
    for (int cc = 0; cc < 8; cc++) {
        int row = cc * 8 + r8;
        int colb = (c8 * 16) ^ (r8 << 4);
        bf16x8 val = *(const bf16x8*)((const char*)Ep + row * 128 + colb);
        *(bf16x8*)(ctx + (size_t)(b * SEQ + qw + row) * HID + h * 64 + c8 * 8) = val;
    }
}

// ---------------- output projection + bias + residual ----------------
__global__ __launch_bounds__(256) void oproj_gemm(
    const bf16* __restrict__ Cb, const bf16* __restrict__ Wo, const float* __restrict__ bo,
    const float* __restrict__ hidden, float* __restrict__ y)
{
    int lane = threadIdx.x & 63;
    int wid  = threadIdx.x >> 6;
    int wm = wid >> 1, wn = wid & 1;
    int g = lane >> 4, c = lane & 15;
    int m0 = blockIdx.y * 128 + wm * 64;
    int n0 = blockIdx.x * 128 + wn * 64;

    f32x4 acc[4][4] = {};
    const bf16* Aptr = Cb + (size_t)(m0 + c) * HID + g * 8;
    const bf16* Bptr = Wo + (size_t)(n0 + c) * HID + g * 8;

    for (int k0 = 0; k0 < HID; k0 += 32) {
        bf16x8 a[4], b[4];
#pragma unroll
        for (int i = 0; i < 4; i++) {
            a[i] = *reinterpret_cast<const bf16x8*>(Aptr + (size_t)i * 16 * HID + k0);
            b[i] = *reinterpret_cast<const bf16x8*>(Bptr + (size_t)i * 16 * HID + k0);
        }
#pragma unroll
        for (int mi = 0; mi < 4; mi++)
#pragma unroll
            for (int ni = 0; ni < 4; ni++)
                acc[mi][ni] = __builtin_amdgcn_mfma_f32_16x16x32_bf16(a[mi], b[ni], acc[mi][ni], 0, 0, 0);
    }

#pragma unroll
    for (int ni = 0; ni < 4; ni++) {
        int n = n0 + ni * 16 + c;
        float bval = bo[n];
#pragma unroll
        for (int mi = 0; mi < 4; mi++) {
#pragma unroll
            for (int j = 0; j < 4; j++) {
                int m = m0 + mi * 16 + g * 4 + j;
                size_t idx = (size_t)m * HID + n;
                y[idx] = acc[mi][ni][j] + bval + hidden[idx];
            }
        }
    }
}

// ---------------- LayerNorm ----------------
__global__ __launch_bounds__(256) void ln_kernel(
    const float* __restrict__ y, const float* __restrict__ gam,
    const float* __restrict__ bet, float* __restrict__ out)
{
    int row = blockIdx.x * 4 + (threadIdx.x >> 6);
    int lane = threadIdx.x & 63;
    const float* yr = y + (size_t)row * HID;

    float4 v[3];
#pragma unroll
    for (int i = 0; i < 3; i++)
        v[i] = reinterpret_cast<const float4*>(yr)[lane + i * 64];

    float s = 0.f;
#pragma unroll
    for (int i = 0; i < 3; i++) s += v[i].x + v[i].y + v[i].z + v[i].w;
#pragma unroll
    for (int msk = 1; msk < 64; msk <<= 1) s += __shfl_xor(s, msk, 64);
    float mean = s * (1.f / 768.f);

    float q = 0.f;
#pragma unroll
    for (int i = 0; i < 3; i++) {
        float dx = v[i].x - mean, dy = v[i].y - mean, dz = v[i].z - mean, dw = v[i].w - mean;
        q += dx * dx + dy * dy + dz * dz + dw * dw;
    }
#pragma unroll
    for (int msk = 1; msk < 64; msk <<= 1) q += __shfl_xor(q, msk, 64);
    float rstd = rsqrtf(q * (1.f / 768.f) + 1e-12f);

    float* outr = out + (size_t)row * HID;
#pragma unroll
    for (int i = 0; i < 3; i++) {
        float4 gg = reinterpret_cast<const float4*>(gam)[lane + i * 64];
        float4 bb = reinterpret_cast<const float4*>(bet)[lane + i * 64];
        float4 o;
        o.x = (v[i].x - mean) * rstd * gg.x + bb.x;
        o.y = (v[i].y - mean) * rstd * gg.y + bb.y;
        o.z = (v[i].z - mean) * rstd * gg.z + bb.z;
        o.w = (v[i].w - mean) * rstd * gg.w + bb.w;
        reinterpret_cast<float4*>(outr)[lane + i * 64] = o;
    }
}

extern "C" void kernel_launch(void* const* d_in, const int* in_sizes, int n_in,
                              void* d_out, int out_size, void* d_ws, size_t ws_size,
                              hipStream_t stream) {
    const float* hidden = (const float*)d_in[0];
    const float* mask   = (const float*)d_in[1];
    const float* q_w = (const float*)d_in[2];
    const float* q_b = (const float*)d_in[3];
    const float* k_w = (const float*)d_in[4];
    const float* k_b = (const float*)d_in[5];
    const float* v_w = (const float*)d_in[6];
    const float* v_b = (const float*)d_in[7];
    const float* o_w = (const float*)d_in[8];
    const float* o_b = (const float*)d_in[9];
    const float* ln_g = (const float*)d_in[10];
    const float* ln_b = (const float*)d_in[11];
    float* out = (float*)d_out;

    const size_t SZ_X = (size_t)MTOT * HID;
    const size_t SZ_W = (size_t)HID * HID;

    char* ws = (char*)d_ws;
    size_t XB_OFF = 0;
    size_t W_OFF  = XB_OFF + SZ_X * 2;
    size_t QH_OFF = W_OFF + 4 * SZ_W * 2;
    size_t KH_OFF = QH_OFF + SZ_X * 2;
    size_t VT_OFF = KH_OFF + SZ_X * 2;

    bf16* Xb  = (bf16*)(ws + XB_OFF);
    bf16* Wqb = (bf16*)(ws + W_OFF);
    bf16* Wkb = Wqb + SZ_W;
    bf16* Wvb = Wkb + SZ_W;
    bf16* Wob = Wvb + SZ_W;
    bf16* Qh  = (bf16*)(ws + QH_OFF);
    bf16* Kh  = (bf16*)(ws + KH_OFF);
    bf16* Vt  = (bf16*)(ws + VT_OFF);
    bf16* ctx = (bf16*)(ws + XB_OFF);
    float* y  = (float*)(ws + QH_OFF);

    cvt_kernel<<<dim3((SZ_X / 4 + 255) / 256), 256, 0, stream>>>(hidden, Xb, SZ_X / 4);
    cvt_kernel<<<dim3((SZ_W / 4 + 255) / 256), 256, 0, stream>>>(q_w, Wqb, SZ_W / 4);
    cvt_kernel<<<dim3((SZ_W / 4 + 255) / 256), 256, 0, stream>>>(k_w, Wkb, SZ_W / 4);
    cvt_kernel<<<dim3((SZ_W / 4 + 255) / 256), 256, 0, stream>>>(v_w, Wvb, SZ_W / 4);
    cvt_kernel<<<dim3((SZ_W / 4 + 255) / 256), 256, 0, stream>>>(o_w, Wob, SZ_W / 4);

    qkv_gemm<<<dim3(HID / 128, MTOT / 128, 3), 256, 0, stream>>>(
        Xb, Wqb, Wkb, Wvb, q_b, k_b, v_b, Qh, Kh, Vt);

    // barrier-free attention: 1 wave per block, 64 q-rows, frag-packed coalesced K/V
    attn_kernel<<<dim3(NB * NHEAD, SEQ / 64), 64, 0, stream>>>(Qh, Kh, Vt, mask, ctx);

    oproj_gemm<<<dim3(HID / 128, MTOT / 128), 256, 0, stream>>>(ctx, Wob, o_b, hidden, y);

    ln_kernel<<<dim3(MTOT / 4), 256, 0, stream>>>(y, ln_g, ln_b, out);
}

// Round 5
// 397.925 us; speedup vs baseline: 1.4613x; 1.2621x over previous
//
#include <hip/hip_runtime.h>

typedef __bf16 bf16;
typedef __bf16 bf16x4 __attribute__((ext_vector_type(4)));
typedef __bf16 bf16x8 __attribute__((ext_vector_type(8)));
typedef float f32x4 __attribute__((ext_vector_type(4)));
typedef float f32x16 __attribute__((ext_vector_type(16)));

#define NB 2
#define SEQ 4096
#define HID 768
#define NHEAD 12
#define HDIM 64
#define MTOT (NB * SEQ)   // 8192
#define LOG2E 1.4426950408889634f

// ---------------- fp32 -> bf16 convert (vectorized) ----------------
__global__ __launch_bounds__(256) void cvt_kernel(const float* __restrict__ in,
                                                  bf16* __restrict__ out, int n4) {
    int stride = gridDim.x * blockDim.x;
    for (int i = blockIdx.x * blockDim.x + threadIdx.x; i < n4; i += stride) {
        float4 v = reinterpret_cast<const float4*>(in)[i];
        bf16x4 o;
        o[0] = (bf16)v.x; o[1] = (bf16)v.y; o[2] = (bf16)v.z; o[3] = (bf16)v.w;
        reinterpret_cast<bf16x4*>(out)[i] = o;
    }
}

// ---------------- fused QKV projection GEMM ----------------
// K and V are written FRAGMENT-PACKED per (bh, 64-row tile):
//   tile = 8 fragments x 64 lanes x 8 bf16 (4096 elems = 8KB).
// K frag f=khalf*4+dc, lane holds K[kt*64+khalf*32+(lane&31)][dc*16+(lane>>5)*8+j]
// V frag f=dhalf*4+kc, lane holds V[kt*64+kc*16+(lane>>5)*8+j][dhalf*32+(lane&31)]
__global__ __launch_bounds__(256) void qkv_gemm(
    const bf16* __restrict__ Xb,
    const bf16* __restrict__ Wq, const bf16* __restrict__ Wk, const bf16* __restrict__ Wv,
    const float* __restrict__ bq, const float* __restrict__ bk, const float* __restrict__ bv,
    bf16* __restrict__ Qh, bf16* __restrict__ Kh, bf16* __restrict__ Vt)
{
    int z = blockIdx.z;
    const bf16* W = (z == 0) ? Wq : (z == 1) ? Wk : Wv;
    const float* bias = (z == 0) ? bq : (z == 1) ? bk : bv;

    int lane = threadIdx.x & 63;
    int wid  = threadIdx.x >> 6;
    int wm = wid >> 1, wn = wid & 1;
    int g = lane >> 4, c = lane & 15;
    int m0 = blockIdx.y * 128 + wm * 64;
    int n0 = blockIdx.x * 128 + wn * 64;

    f32x4 acc[4][4] = {};
    const bf16* Aptr = Xb + (size_t)(m0 + c) * HID + g * 8;
    const bf16* Bptr = W  + (size_t)(n0 + c) * HID + g * 8;

    for (int k0 = 0; k0 < HID; k0 += 32) {
        bf16x8 a[4], b[4];
#pragma unroll
        for (int i = 0; i < 4; i++) {
            a[i] = *reinterpret_cast<const bf16x8*>(Aptr + (size_t)i * 16 * HID + k0);
            b[i] = *reinterpret_cast<const bf16x8*>(Bptr + (size_t)i * 16 * HID + k0);
        }
#pragma unroll
        for (int mi = 0; mi < 4; mi++)
#pragma unroll
            for (int ni = 0; ni < 4; ni++)
                acc[mi][ni] = __builtin_amdgcn_mfma_f32_16x16x32_bf16(a[mi], b[ni], acc[mi][ni], 0, 0, 0);
    }

#pragma unroll
    for (int ni = 0; ni < 4; ni++) {
        int n = n0 + ni * 16 + c;
        float bval = bias[n];
        int h = n >> 6, d = n & 63;
#pragma unroll
        for (int mi = 0; mi < 4; mi++) {
#pragma unroll
            for (int j = 0; j < 4; j++) {
                int m = m0 + mi * 16 + g * 4 + j;
                float val = acc[mi][ni][j] + bval;
                int bb = m >> 12, s = m & 4095;
                size_t bhb = (size_t)(bb * NHEAD + h) * SEQ * HDIM;
                if (z == 0) {
                    // pre-scale Q by 1/sqrt(HD) * log2(e) for exp2-domain softmax
                    val *= 0.125f * LOG2E;
                    Qh[bhb + (size_t)s * HDIM + d] = (bf16)val;
                } else if (z == 1) {
                    int fragidx = (((s >> 5) & 1) << 2) | (d >> 4);
                    int lane2 = (s & 31) | (((d >> 3) & 1) << 5);
                    Kh[bhb + (size_t)(s >> 6) * 4096 + fragidx * 512 + lane2 * 8 + (d & 7)] = (bf16)val;
                } else {
                    int fragidx = ((d >> 5) << 2) | ((s >> 4) & 3);
                    int lane2 = (d & 31) | (((s >> 3) & 1) << 5);
                    Vt[bhb + (size_t)(s >> 6) * 4096 + fragidx * 512 + lane2 * 8 + (s & 7)] = (bf16)val;
                }
            }
        }
    }
}

// ---------------- softmax helpers ----------------
__device__ inline void smax_update(f32x16& sA, f32x16& sB, float& m, float& l,
                                   f32x16& oA, f32x16& oB) {
    float r[16];
#pragma unroll
    for (int i = 0; i < 16; i++) r[i] = fmaxf(sA[i], sB[i]);
#pragma unroll
    for (int st = 8; st; st >>= 1)
#pragma unroll
        for (int i = 0; i < st; i++) r[i] = fmaxf(r[i], r[i + st]);
    float t = fmaxf(r[0], __shfl_xor(r[0], 32));
    if (__any(t > m + 8.f)) {          // defer-max (T13)
        float mn = fmaxf(m, t);
        float al = __builtin_amdgcn_exp2f(m - mn);
        m = mn; l *= al;
#pragma unroll
        for (int i = 0; i < 16; i++) { oA[i] *= al; oB[i] *= al; }
    }
#pragma unroll
    for (int i = 0; i < 16; i++) {
        sA[i] = __builtin_amdgcn_exp2f(sA[i] - m);
        sB[i] = __builtin_amdgcn_exp2f(sB[i] - m);
    }
    float q[16];
#pragma unroll
    for (int i = 0; i < 16; i++) q[i] = sA[i] + sB[i];
#pragma unroll
    for (int st = 8; st; st >>= 1)
#pragma unroll
        for (int i = 0; i < st; i++) q[i] += q[i + st];
    l += q[0] + __shfl_xor(q[0], 32);
}

// P (f32 D-layout, khalf pair) -> 4 bf16 B-frags via cvt_pk + permlane32_swap
__device__ inline void pconv(f32x16& sA, f32x16& sB, bf16x8* pa) {
#pragma unroll
    for (int ks = 0; ks < 2; ks++) {
        f32x16& sc = ks ? sB : sA;
        unsigned u[8];
#pragma unroll
        for (int i = 0; i < 8; i++) {
            union { bf16 hh[2]; unsigned uu; } x;
            x.hh[0] = (bf16)sc[i * 2];
            x.hh[1] = (bf16)sc[i * 2 + 1];
            u[i] = x.uu;
        }
        asm("v_permlane32_swap_b32 %0, %1" : "+v"(u[0]), "+v"(u[2]));
        asm("v_permlane32_swap_b32 %0, %1" : "+v"(u[1]), "+v"(u[3]));
        asm("v_permlane32_swap_b32 %0, %1" : "+v"(u[4]), "+v"(u[6]));
        asm("v_permlane32_swap_b32 %0, %1" : "+v"(u[5]), "+v"(u[7]));
        union { unsigned uu[4]; bf16x8 v; } f0, f1;
        f0.uu[0] = u[0]; f0.uu[1] = u[1]; f0.uu[2] = u[2]; f0.uu[3] = u[3];
        f1.uu[0] = u[4]; f1.uu[1] = u[5]; f1.uu[2] = u[6]; f1.uu[3] = u[7];
        pa[ks * 2]     = f0.v;
        pa[ks * 2 + 1] = f1.v;
    }
}

// ---------------- flash attention (split-K over 2 waves, frag-packed K/V) ----------------
// grid: (NB*NHEAD, SEQ/64); 128 threads = 2 waves, both own the same 64 q-rows.
// Wave w processes kt = w, w+2, ... (32 tiles); merge partial (m,l,o) at the end.
// XCD = blockid%8 = bh%8 -> 3 heads per XCD (3MB K/V, L2-resident).
__global__ __launch_bounds__(128) void attn_kernel(
    const bf16* __restrict__ Qh, const bf16* __restrict__ Kh, const bf16* __restrict__ Vt,
    const float* __restrict__ mask, bf16* __restrict__ ctx)
{
    __shared__ float Sm[4096];         // 16KB: wave1 o-state (chunk-interleaved: [i][lane])
    __shared__ float Sml[256];         // 1KB:  wave1 m/l state
    __shared__ bf16 Ep[4096];          // 8KB:  epilogue coalesce buffer

    const int lane = threadIdx.x & 63;
    const int w = threadIdx.x >> 6;    // 0 or 1
    const int lq = lane & 31;
    const int hi = lane >> 5;
    const int bh = blockIdx.x;
    const int b = bh / NHEAD, h = bh % NHEAD;
    const size_t base = (size_t)bh * SEQ * HDIM;
    const int qw = blockIdx.y * 64;

    // Q B-frags (pre-scaled): qf{0,1}[dc] -> lane holds Q[qw+qh*32+lq][dc*16+hi*8+j]
    bf16x8 qf0[4], qf1[4];
#pragma unroll
    for (int dc = 0; dc < 4; dc++) {
        qf0[dc] = *(const bf16x8*)(Qh + base + (size_t)(qw + lq) * HDIM + dc * 16 + hi * 8);
        qf1[dc] = *(const bf16x8*)(Qh + base + (size_t)(qw + 32 + lq) * HDIM + dc * 16 + hi * 8);
    }
    const float* maskb = mask + b * SEQ;

    const bf16* kfrag = Kh + base + (size_t)lane * 8;
    const bf16* vfrag = Vt + base + (size_t)lane * 8;

    float m0 = -3e38f, m1 = -3e38f, l0 = 0.f, l1 = 0.f;
    f32x16 o00 = {}, o01 = {}, o10 = {}, o11 = {};   // o[qhalf][dhalf]

    for (int kt = w; kt < SEQ / 64; kt += 2) {
        const bf16* kb_ = kfrag + (size_t)kt * 4096;
        const bf16* vb_ = vfrag + (size_t)kt * 4096;
        bf16x8 kf[8], vf[8];
#pragma unroll
        for (int f = 0; f < 8; f++) kf[f] = *(const bf16x8*)(kb_ + f * 512);
#pragma unroll
        for (int f = 0; f < 8; f++) vf[f] = *(const bf16x8*)(vb_ + f * 512);

        // ---- QK^T: s[qhalf][khalf] = K * Q^T, D[k][q] ----
        f32x16 s00 = {}, s01 = {}, s10 = {}, s11 = {};
#pragma unroll
        for (int dc = 0; dc < 4; dc++) {
            s00 = __builtin_amdgcn_mfma_f32_32x32x16_bf16(kf[dc],     qf0[dc], s00, 0, 0, 0);
            s01 = __builtin_amdgcn_mfma_f32_32x32x16_bf16(kf[4 + dc], qf0[dc], s01, 0, 0, 0);
            s10 = __builtin_amdgcn_mfma_f32_32x32x16_bf16(kf[dc],     qf1[dc], s10, 0, 0, 0);
            s11 = __builtin_amdgcn_mfma_f32_32x32x16_bf16(kf[4 + dc], qf1[dc], s11, 0, 0, 0);
        }

        // ---- mask add (exp2 domain), shared across qhalves ----
        const float* mrow = maskb + kt * 64 + hi * 4;
#pragma unroll
        for (int ks = 0; ks < 2; ks++) {
#pragma unroll
            for (int g = 0; g < 4; g++) {
                f32x4 mk = *(const f32x4*)(mrow + ks * 32 + g * 8);
#pragma unroll
                for (int j = 0; j < 4; j++) {
                    float mval = mk[j] * LOG2E;
                    if (ks == 0) { s00[g * 4 + j] += mval; s10[g * 4 + j] += mval; }
                    else         { s01[g * 4 + j] += mval; s11[g * 4 + j] += mval; }
                }
            }
        }

        // ---- softmax + P conversion, qhalf 0 then 1 ----
        bf16x8 pa0[4], pa1[4];
        smax_update(s00, s01, m0, l0, o00, o01);
        pconv(s00, s01, pa0);
        smax_update(s10, s11, m1, l1, o10, o11);
        pconv(s10, s11, pa1);

        // ---- PV: o[qhalf][dhalf] += V^T * P^T ----
#pragma unroll
        for (int kc = 0; kc < 4; kc++) {
            o00 = __builtin_amdgcn_mfma_f32_32x32x16_bf16(vf[kc],     pa0[kc], o00, 0, 0, 0);
            o01 = __builtin_amdgcn_mfma_f32_32x32x16_bf16(vf[4 + kc], pa0[kc], o01, 0, 0, 0);
            o10 = __builtin_amdgcn_mfma_f32_32x32x16_bf16(vf[kc],     pa1[kc], o10, 0, 0, 0);
            o11 = __builtin_amdgcn_mfma_f32_32x32x16_bf16(vf[4 + kc], pa1[kc], o11, 0, 0, 0);
        }
    }

    // ---- cross-wave merge: wave1 parks state in LDS, wave0 combines ----
    if (w == 1) {
#pragma unroll
        for (int i = 0; i < 16; i++) {
            Sm[i * 64 + lane]        = o00[i];
            Sm[(16 + i) * 64 + lane] = o01[i];
            Sm[(32 + i) * 64 + lane] = o10[i];
            Sm[(48 + i) * 64 + lane] = o11[i];
        }
        Sml[0 * 64 + lane] = m0; Sml[1 * 64 + lane] = l0;
        Sml[2 * 64 + lane] = m1; Sml[3 * 64 + lane] = l1;
    }
    __syncthreads();
    if (w == 1) return;

    {
        float mB0 = Sml[0 * 64 + lane], lB0 = Sml[1 * 64 + lane];
        float mB1 = Sml[2 * 64 + lane], lB1 = Sml[3 * 64 + lane];
        float mm = fmaxf(m0, mB0);
        float a = __builtin_amdgcn_exp2f(m0 - mm);
        float bb_ = __builtin_amdgcn_exp2f(mB0 - mm);
        l0 = l0 * a + lB0 * bb_;
#pragma unroll
        for (int i = 0; i < 16; i++) {
            o00[i] = o00[i] * a + Sm[i * 64 + lane] * bb_;
            o01[i] = o01[i] * a + Sm[(16 + i) * 64 + lane] * bb_;
        }
        mm = fmaxf(m1, mB1);
        a = __builtin_amdgcn_exp2f(m1 - mm);
        bb_ = __builtin_amdgcn_exp2f(mB1 - mm);
        l1 = l1 * a + lB1 * bb_;
#pragma unroll
        for (int i = 0; i < 16; i++) {
            o10[i] = o10[i] * a + Sm[(32 + i) * 64 + lane] * bb_;
            o11[i] = o11[i] * a + Sm[(48 + i) * 64 + lane] * bb_;
        }
    }

    // ---- epilogue (wave0 only): O/l -> LDS (coalesce, swizzled) -> global ----
    float inv0 = 1.f / l0, inv1 = 1.f / l1;
#pragma unroll
    for (int qh = 0; qh < 2; qh++) {
        f32x16& a = qh ? o10 : o00;
        f32x16& bq_ = qh ? o11 : o01;
        float inv = qh ? inv1 : inv0;
        int q = qh * 32 + lq;
        int sw = (q & 7) << 4;
#pragma unroll
        for (int g = 0; g < 4; g++) {
            bf16x4 p0, p1;
#pragma unroll
            for (int j = 0; j < 4; j++) {
                p0[j] = (bf16)(a[g * 4 + j] * inv);
                p1[j] = (bf16)(bq_[g * 4 + j] * inv);
            }
            int colb = g * 16 + hi * 8;
            *(bf16x4*)((char*)Ep + q * 128 + (colb ^ sw)) = p0;
            *(bf16x4*)((char*)Ep + q * 128 + ((64 + colb) ^ sw)) = p1;
        }
    }
    const int r8 = lane >> 3;
    const int c8 = lane & 7;
#pragma unroll
    for (int cc = 0; cc < 8; cc++) {
        int row = cc * 8 + r8;
        int colb = (c8 * 16) ^ (r8 << 4);
        bf16x8 val = *(const bf16x8*)((const char*)Ep + row * 128 + colb);
        *(bf16x8*)(ctx + (size_t)(b * SEQ + qw + row) * HID + h * 64 + c8 * 8) = val;
    }
}

// ---------------- output projection + bias + residual ----------------
__global__ __launch_bounds__(256) void oproj_gemm(
    const bf16* __restrict__ Cb, const bf16* __restrict__ Wo, const float* __restrict__ bo,
    const float* __restrict__ hidden, float* __restrict__ y)
{
    int lane = threadIdx.x & 63;
    int wid  = threadIdx.x >> 6;
    int wm = wid >> 1, wn = wid & 1;
    int g = lane >> 4, c = lane & 15;
    int m0 = blockIdx.y * 128 + wm * 64;
    int n0 = blockIdx.x * 128 + wn * 64;

    f32x4 acc[4][4] = {};
    const bf16* Aptr = Cb + (size_t)(m0 + c) * HID + g * 8;
    const bf16* Bptr = Wo + (size_t)(n0 + c) * HID + g * 8;

    for (int k0 = 0; k0 < HID; k0 += 32) {
        bf16x8 a[4], b[4];
#pragma unroll
        for (int i = 0; i < 4; i++) {
            a[i] = *reinterpret_cast<const bf16x8*>(Aptr + (size_t)i * 16 * HID + k0);
            b[i] = *reinterpret_cast<const bf16x8*>(Bptr + (size_t)i * 16 * HID + k0);
        }
#pragma unroll
        for (int mi = 0; mi < 4; mi++)
#pragma unroll
            for (int ni = 0; ni < 4; ni++)
                acc[mi][ni] = __builtin_amdgcn_mfma_f32_16x16x32_bf16(a[mi], b[ni], acc[mi][ni], 0, 0, 0);
    }

#pragma unroll
    for (int ni = 0; ni < 4; ni++) {
        int n = n0 + ni * 16 + c;
        float bval = bo[n];
#pragma unroll
        for (int mi = 0; mi < 4; mi++) {
#pragma unroll
            for (int j = 0; j < 4; j++) {
                int m = m0 + mi * 16 + g * 4 + j;
                size_t idx = (size_t)m * HID + n;
                y[idx] = acc[mi][ni][j] + bval + hidden[idx];
            }
        }
    }
}

// ---------------- LayerNorm ----------------
__global__ __launch_bounds__(256) void ln_kernel(
    const float* __restrict__ y, const float* __restrict__ gam,
    const float* __restrict__ bet, float* __restrict__ out)
{
    int row = blockIdx.x * 4 + (threadIdx.x >> 6);
    int lane = threadIdx.x & 63;
    const float* yr = y + (size_t)row * HID;

    float4 v[3];
#pragma unroll
    for (int i = 0; i < 3; i++)
        v[i] = reinterpret_cast<const float4*>(yr)[lane + i * 64];

    float s = 0.f;
#pragma unroll
    for (int i = 0; i < 3; i++) s += v[i].x + v[i].y + v[i].z + v[i].w;
#pragma unroll
    for (int msk = 1; msk < 64; msk <<= 1) s += __shfl_xor(s, msk, 64);
    float mean = s * (1.f / 768.f);

    float q = 0.f;
#pragma unroll
    for (int i = 0; i < 3; i++) {
        float dx = v[i].x - mean, dy = v[i].y - mean, dz = v[i].z - mean, dw = v[i].w - mean;
        q += dx * dx + dy * dy + dz * dz + dw * dw;
    }
#pragma unroll
    for (int msk = 1; msk < 64; msk <<= 1) q += __shfl_xor(q, msk, 64);
    float rstd = rsqrtf(q * (1.f / 768.f) + 1e-12f);

    float* outr = out + (size_t)row * HID;
#pragma unroll
    for (int i = 0; i < 3; i++) {
        float4 gg = reinterpret_cast<const float4*>(gam)[lane + i * 64];
        float4 bb = reinterpret_cast<const float4*>(bet)[lane + i * 64];
        float4 o;
        o.x = (v[i].x - mean) * rstd * gg.x + bb.x;
        o.y = (v[i].y - mean) * rstd * gg.y + bb.y;
        o.z = (v[i].z - mean) * rstd * gg.z + bb.z;
        o.w = (v[i].w - mean) * rstd * gg.w + bb.w;
        reinterpret_cast<float4*>(outr)[lane + i * 64] = o;
    }
}

extern "C" void kernel_launch(void* const* d_in, const int* in_sizes, int n_in,
                              void* d_out, int out_size, void* d_ws, size_t ws_size,
                              hipStream_t stream) {
    const float* hidden = (const float*)d_in[0];
    const float* mask   = (const float*)d_in[1];
    const float* q_w = (const float*)d_in[2];
    const float* q_b = (const float*)d_in[3];
    const float* k_w = (const float*)d_in[4];
    const float* k_b = (const float*)d_in[5];
    const float* v_w = (const float*)d_in[6];
    const float* v_b = (const float*)d_in[7];
    const float* o_w = (const float*)d_in[8];
    const float* o_b = (const float*)d_in[9];
    const float* ln_g = (const float*)d_in[10];
    const float* ln_b = (const float*)d_in[11];
    float* out = (float*)d_out;

    const size_t SZ_X = (size_t)MTOT * HID;
    const size_t SZ_W = (size_t)HID * HID;

    char* ws = (char*)d_ws;
    size_t XB_OFF = 0;
    size_t W_OFF  = XB_OFF + SZ_X * 2;
    size_t QH_OFF = W_OFF + 4 * SZ_W * 2;
    size_t KH_OFF = QH_OFF + SZ_X * 2;
    size_t VT_OFF = KH_OFF + SZ_X * 2;

    bf16* Xb  = (bf16*)(ws + XB_OFF);
    bf16* Wqb = (bf16*)(ws + W_OFF);
    bf16* Wkb = Wqb + SZ_W;
    bf16* Wvb = Wkb + SZ_W;
    bf16* Wob = Wvb + SZ_W;
    bf16* Qh  = (bf16*)(ws + QH_OFF);
    bf16* Kh  = (bf16*)(ws + KH_OFF);
    bf16* Vt  = (bf16*)(ws + VT_OFF);
    bf16* ctx = (bf16*)(ws + XB_OFF);
    float* y  = (float*)(ws + QH_OFF);

    cvt_kernel<<<dim3((SZ_X / 4 + 255) / 256), 256, 0, stream>>>(hidden, Xb, SZ_X / 4);
    cvt_kernel<<<dim3((SZ_W / 4 + 255) / 256), 256, 0, stream>>>(q_w, Wqb, SZ_W / 4);
    cvt_kernel<<<dim3((SZ_W / 4 + 255) / 256), 256, 0, stream>>>(k_w, Wkb, SZ_W / 4);
    cvt_kernel<<<dim3((SZ_W / 4 + 255) / 256), 256, 0, stream>>>(v_w, Wvb, SZ_W / 4);
    cvt_kernel<<<dim3((SZ_W / 4 + 255) / 256), 256, 0, stream>>>(o_w, Wob, SZ_W / 4);

    qkv_gemm<<<dim3(HID / 128, MTOT / 128, 3), 256, 0, stream>>>(
        Xb, Wqb, Wkb, Wvb, q_b, k_b, v_b, Qh, Kh, Vt);

    // split-K attention: 2 waves per block share 64 q-rows, merge at end
    attn_kernel<<<dim3(NB * NHEAD, SEQ / 64), 128, 0, stream>>>(Qh, Kh, Vt, mask, ctx);

    oproj_gemm<<<dim3(HID / 128, MTOT / 128), 256, 0, stream>>>(ctx, Wob, o_b, hidden, y);

    ln_kernel<<<dim3(MTOT / 4), 256, 0, stream>>>(y, ln_g, ln_b, out);
}

// Round 6
// 297.647 us; speedup vs baseline: 1.9535x; 1.3369x over previous
//
#include <hip/hip_runtime.h>

typedef __bf16 bf16;
typedef __bf16 bf16x4 __attribute__((ext_vector_type(4)));
typedef __bf16 bf16x8 __attribute__((ext_vector_type(8)));
typedef float f32x4 __attribute__((ext_vector_type(4)));
typedef float f32x16 __attribute__((ext_vector_type(16)));

#define NB 2
#define SEQ 4096
#define HID 768
#define NHEAD 12
#define HDIM 64
#define MTOT (NB * SEQ)   // 8192
#define LOG2E 1.4426950408889634f

// ============ fragment-pack kernels ============
// A/B-frag layout for mfma_f32_16x16x32_bf16 over a row-major [R][768] fp32 matrix:
// out[((rtile*24 + kstep)*64 + lane)*8 + j] = in[rtile*16 + (lane&15)][kstep*32 + (lane>>4)*8 + j]
__device__ inline void pack_body(const float* __restrict__ in, bf16* __restrict__ out, int rt) {
    __shared__ alignas(16) bf16 T[16 * 264];
    const int lane = threadIdx.x;
    const int c = lane & 15, g = lane >> 4;
    const float4* in4 = (const float4*)in + (size_t)rt * 16 * (HID / 4);
    for (int chunk = 0; chunk < 3; chunk++) {
#pragma unroll
        for (int i = 0; i < 16; i++) {
            float4 v = in4[(size_t)i * (HID / 4) + chunk * 64 + lane];
            bf16x4 o;
            o[0] = (bf16)v.x; o[1] = (bf16)v.y; o[2] = (bf16)v.z; o[3] = (bf16)v.w;
            *(bf16x4*)&T[i * 264 + lane * 4] = o;
        }
        __syncthreads();
#pragma unroll
        for (int s = 0; s < 8; s++) {
            bf16x8 val = *(const bf16x8*)&T[c * 264 + s * 32 + g * 8];
            *(bf16x8*)(out + (((size_t)rt * 24 + chunk * 8 + s) * 64 + lane) * 8) = val;
        }
        __syncthreads();
    }
}

__global__ __launch_bounds__(64) void pack_a(const float* __restrict__ in, bf16* __restrict__ out) {
    pack_body(in, out, blockIdx.x);
}

__global__ __launch_bounds__(64) void pack_w4(
    const float* __restrict__ w0, const float* __restrict__ w1,
    const float* __restrict__ w2, const float* __restrict__ w3,
    bf16* __restrict__ o0, bf16* __restrict__ o1, bf16* __restrict__ o2, bf16* __restrict__ o3) {
    int y = blockIdx.y;
    const float* in = (y == 0) ? w0 : (y == 1) ? w1 : (y == 2) ? w2 : w3;
    bf16* out = (y == 0) ? o0 : (y == 1) ? o1 : (y == 2) ? o2 : o3;
    pack_body(in, out, blockIdx.x);
}

// ============ fused QKV projection GEMM (packed operands) ============
// K and V outputs are written FRAGMENT-PACKED per (bh, 64-row tile) for attn;
// Q row-major (pre-scaled by 0.125*log2e).
__global__ __launch_bounds__(256, 2) void qkv_gemm(
    const bf16* __restrict__ Xp,
    const bf16* __restrict__ Wq, const bf16* __restrict__ Wk, const bf16* __restrict__ Wv,
    const float* __restrict__ bq, const float* __restrict__ bk, const float* __restrict__ bv,
    bf16* __restrict__ Qh, bf16* __restrict__ Kh, bf16* __restrict__ Vt)
{
    int z = blockIdx.z;
    const bf16* W = (z == 0) ? Wq : (z == 1) ? Wk : Wv;
    const float* bias = (z == 0) ? bq : (z == 1) ? bk : bv;

    int lane = threadIdx.x & 63;
    int wid  = threadIdx.x >> 6;
    int wm = wid >> 1, wn = wid & 1;
    int g = lane >> 4, c = lane & 15;
    int m0 = blockIdx.y * 128 + wm * 64;
    int n0 = blockIdx.x * 128 + wn * 64;

    f32x4 acc[4][4] = {};
    const bf16* Ap = Xp + ((size_t)(m0 >> 4) * 24) * 512 + (size_t)lane * 8;
    const bf16* Bp = W  + ((size_t)(n0 >> 4) * 24) * 512 + (size_t)lane * 8;

    for (int ks = 0; ks < 24; ks++) {
        bf16x8 a[4], b[4];
#pragma unroll
        for (int i = 0; i < 4; i++) {
            a[i] = *(const bf16x8*)(Ap + ((size_t)i * 24 + ks) * 512);
            b[i] = *(const bf16x8*)(Bp + ((size_t)i * 24 + ks) * 512);
        }
#pragma unroll
        for (int mi = 0; mi < 4; mi++)
#pragma unroll
            for (int ni = 0; ni < 4; ni++)
                acc[mi][ni] = __builtin_amdgcn_mfma_f32_16x16x32_bf16(a[mi], b[ni], acc[mi][ni], 0, 0, 0);
    }

#pragma unroll
    for (int ni = 0; ni < 4; ni++) {
        int n = n0 + ni * 16 + c;
        float bval = bias[n];
        int h = n >> 6, d = n & 63;
#pragma unroll
        for (int mi = 0; mi < 4; mi++) {
#pragma unroll
            for (int j = 0; j < 4; j++) {
                int m = m0 + mi * 16 + g * 4 + j;
                float val = acc[mi][ni][j] + bval;
                int bb = m >> 12, s = m & 4095;
                size_t bhb = (size_t)(bb * NHEAD + h) * SEQ * HDIM;
                if (z == 0) {
                    val *= 0.125f * LOG2E;
                    Qh[bhb + (size_t)s * HDIM + d] = (bf16)val;
                } else if (z == 1) {
                    int fragidx = (((s >> 5) & 1) << 2) | (d >> 4);
                    int lane2 = (s & 31) | (((d >> 3) & 1) << 5);
                    Kh[bhb + (size_t)(s >> 6) * 4096 + fragidx * 512 + lane2 * 8 + (d & 7)] = (bf16)val;
                } else {
                    int fragidx = ((d >> 5) << 2) | ((s >> 4) & 3);
                    int lane2 = (d & 31) | (((s >> 3) & 1) << 5);
                    Vt[bhb + (size_t)(s >> 6) * 4096 + fragidx * 512 + lane2 * 8 + (s & 7)] = (bf16)val;
                }
            }
        }
    }
}

// ============ softmax helpers ============
__device__ inline float xhalf_max(float x) {
    float a_ = x, b_ = x;
    asm("v_permlane32_swap_b32 %0, %1" : "+v"(a_), "+v"(b_));
    return fmaxf(a_, b_);
}
__device__ inline float xhalf_sum(float x) {
    float a_ = x, b_ = x;
    asm("v_permlane32_swap_b32 %0, %1" : "+v"(a_), "+v"(b_));
    return a_ + b_;
}

__device__ inline void smax_update(f32x16& sA, f32x16& sB, float& m, float& l,
                                   f32x16& oA, f32x16& oB) {
    float r[16];
#pragma unroll
    for (int i = 0; i < 16; i++) r[i] = fmaxf(sA[i], sB[i]);
#pragma unroll
    for (int st = 8; st; st >>= 1)
#pragma unroll
        for (int i = 0; i < st; i++) r[i] = fmaxf(r[i], r[i + st]);
    float t = xhalf_max(r[0]);
    if (__any(t > m + 8.f)) {          // defer-max (T13)
        float mn = fmaxf(m, t);
        float al = __builtin_amdgcn_exp2f(m - mn);
        m = mn; l *= al;
#pragma unroll
        for (int i = 0; i < 16; i++) { oA[i] *= al; oB[i] *= al; }
    }
#pragma unroll
    for (int i = 0; i < 16; i++) {
        sA[i] = __builtin_amdgcn_exp2f(sA[i] - m);
        sB[i] = __builtin_amdgcn_exp2f(sB[i] - m);
    }
    float q[16];
#pragma unroll
    for (int i = 0; i < 16; i++) q[i] = sA[i] + sB[i];
#pragma unroll
    for (int st = 8; st; st >>= 1)
#pragma unroll
        for (int i = 0; i < st; i++) q[i] += q[i + st];
    l += xhalf_sum(q[0]);
}

__device__ inline void pconv(f32x16& sA, f32x16& sB, bf16x8* pa) {
#pragma unroll
    for (int ks = 0; ks < 2; ks++) {
        f32x16& sc = ks ? sB : sA;
        unsigned u[8];
#pragma unroll
        for (int i = 0; i < 8; i++) {
            union { bf16 hh[2]; unsigned uu; } x;
            x.hh[0] = (bf16)sc[i * 2];
            x.hh[1] = (bf16)sc[i * 2 + 1];
            u[i] = x.uu;
        }
        asm("v_permlane32_swap_b32 %0, %1" : "+v"(u[0]), "+v"(u[2]));
        asm("v_permlane32_swap_b32 %0, %1" : "+v"(u[1]), "+v"(u[3]));
        asm("v_permlane32_swap_b32 %0, %1" : "+v"(u[4]), "+v"(u[6]));
        asm("v_permlane32_swap_b32 %0, %1" : "+v"(u[5]), "+v"(u[7]));
        union { unsigned uu[4]; bf16x8 v; } f0, f1;
        f0.uu[0] = u[0]; f0.uu[1] = u[1]; f0.uu[2] = u[2]; f0.uu[3] = u[3];
        f1.uu[0] = u[4]; f1.uu[1] = u[5]; f1.uu[2] = u[6]; f1.uu[3] = u[7];
        pa[ks * 2]     = f0.v;
        pa[ks * 2 + 1] = f1.v;
    }
}

// ============ flash attention (split-K 2 waves, K/V reg time-share) ============
// grid: (NB*NHEAD, SEQ/64); 128 threads = 2 waves over same 64 q-rows, kt parity split.
// launch_bounds(128,2): cap total regs at 256 -> 2 waves/SIMD resident.
__global__ __launch_bounds__(128, 2) void attn_kernel(
    const bf16* __restrict__ Qh, const bf16* __restrict__ Kh, const bf16* __restrict__ Vt,
    const float* __restrict__ mask, bf16* __restrict__ ctxp)
{
    __shared__ float Sm[4096];
    __shared__ float Sml[256];
    __shared__ alignas(16) bf16 Ep[4096];

    const int lane = threadIdx.x & 63;
    const int w = threadIdx.x >> 6;
    const int lq = lane & 31;
    const int hi = lane >> 5;
    const int bh = blockIdx.x;
    const int b = bh / NHEAD, h = bh % NHEAD;
    const size_t base = (size_t)bh * SEQ * HDIM;
    const int qw = blockIdx.y * 64;

    bf16x8 qf0[4], qf1[4];
#pragma unroll
    for (int dc = 0; dc < 4; dc++) {
        qf0[dc] = *(const bf16x8*)(Qh + base + (size_t)(qw + lq) * HDIM + dc * 16 + hi * 8);
        qf1[dc] = *(const bf16x8*)(Qh + base + (size_t)(qw + 32 + lq) * HDIM + dc * 16 + hi * 8);
    }
    const float* maskb = mask + b * SEQ;

    const bf16* kfrag = Kh + base + (size_t)lane * 8;
    const bf16* vfrag = Vt + base + (size_t)lane * 8;

    float m0 = -3e38f, m1 = -3e38f, l0 = 0.f, l1 = 0.f;
    f32x16 o00 = {}, o01 = {}, o10 = {}, o11 = {};

    for (int kt = w; kt < SEQ / 64; kt += 2) {
        const bf16* kb_ = kfrag + (size_t)kt * 4096;
        const bf16* vb_ = vfrag + (size_t)kt * 4096;
        bf16x8 kv[8];
#pragma unroll
        for (int f = 0; f < 8; f++) kv[f] = *(const bf16x8*)(kb_ + f * 512);

        f32x16 s00 = {}, s01 = {}, s10 = {}, s11 = {};
#pragma unroll
        for (int dc = 0; dc < 4; dc++) {
            s00 = __builtin_amdgcn_mfma_f32_32x32x16_bf16(kv[dc], qf0[dc], s00, 0, 0, 0);
            s10 = __builtin_amdgcn_mfma_f32_32x32x16_bf16(kv[dc], qf1[dc], s10, 0, 0, 0);
        }
#pragma unroll
        for (int dc = 0; dc < 4; dc++) {
            s01 = __builtin_amdgcn_mfma_f32_32x32x16_bf16(kv[4 + dc], qf0[dc], s01, 0, 0, 0);
            s11 = __builtin_amdgcn_mfma_f32_32x32x16_bf16(kv[4 + dc], qf1[dc], s11, 0, 0, 0);
        }

        // K regs dead -> issue V loads now; latency hides under softmax
#pragma unroll
        for (int f = 0; f < 8; f++) kv[f] = *(const bf16x8*)(vb_ + f * 512);

        const float* mrow = maskb + kt * 64 + hi * 4;
#pragma unroll
        for (int ks = 0; ks < 2; ks++) {
#pragma unroll
            for (int g = 0; g < 4; g++) {
                f32x4 mk = *(const f32x4*)(mrow + ks * 32 + g * 8);
#pragma unroll
                for (int j = 0; j < 4; j++) {
                    float mval = mk[j] * LOG2E;
                    if (ks == 0) { s00[g * 4 + j] += mval; s10[g * 4 + j] += mval; }
                    else         { s01[g * 4 + j] += mval; s11[g * 4 + j] += mval; }
                }
            }
        }

        bf16x8 pa0[4], pa1[4];
        smax_update(s00, s01, m0, l0, o00, o01);
        pconv(s00, s01, pa0);
        smax_update(s10, s11, m1, l1, o10, o11);
        pconv(s10, s11, pa1);

#pragma unroll
        for (int kc = 0; kc < 4; kc++) {
            o00 = __builtin_amdgcn_mfma_f32_32x32x16_bf16(kv[kc],     pa0[kc], o00, 0, 0, 0);
            o01 = __builtin_amdgcn_mfma_f32_32x32x16_bf16(kv[4 + kc], pa0[kc], o01, 0, 0, 0);
            o10 = __builtin_amdgcn_mfma_f32_32x32x16_bf16(kv[kc],     pa1[kc], o10, 0, 0, 0);
            o11 = __builtin_amdgcn_mfma_f32_32x32x16_bf16(kv[4 + kc], pa1[kc], o11, 0, 0, 0);
        }
    }

    // ---- cross-wave merge ----
    if (w == 1) {
#pragma unroll
        for (int i = 0; i < 16; i++) {
            Sm[i * 64 + lane]        = o00[i];
            Sm[(16 + i) * 64 + lane] = o01[i];
            Sm[(32 + i) * 64 + lane] = o10[i];
            Sm[(48 + i) * 64 + lane] = o11[i];
        }
        Sml[0 * 64 + lane] = m0; Sml[1 * 64 + lane] = l0;
        Sml[2 * 64 + lane] = m1; Sml[3 * 64 + lane] = l1;
    }
    __syncthreads();
    if (w == 1) return;

    {
        float mB0 = Sml[0 * 64 + lane], lB0 = Sml[1 * 64 + lane];
        float mB1 = Sml[2 * 64 + lane], lB1 = Sml[3 * 64 + lane];
        float mm = fmaxf(m0, mB0);
        float a = __builtin_amdgcn_exp2f(m0 - mm);
        float bb_ = __builtin_amdgcn_exp2f(mB0 - mm);
        l0 = l0 * a + lB0 * bb_;
#pragma unroll
        for (int i = 0; i < 16; i++) {
            o00[i] = o00[i] * a + Sm[i * 64 + lane] * bb_;
            o01[i] = o01[i] * a + Sm[(16 + i) * 64 + lane] * bb_;
        }
        mm = fmaxf(m1, mB1);
        a = __builtin_amdgcn_exp2f(m1 - mm);
        bb_ = __builtin_amdgcn_exp2f(mB1 - mm);
        l1 = l1 * a + lB1 * bb_;
#pragma unroll
        for (int i = 0; i < 16; i++) {
            o10[i] = o10[i] * a + Sm[(32 + i) * 64 + lane] * bb_;
            o11[i] = o11[i] * a + Sm[(48 + i) * 64 + lane] * bb_;
        }
    }

    // ---- epilogue: O/l -> Ep (swizzled) -> ctx FRAG-PACKED for oproj ----
    float inv0 = 1.f / l0, inv1 = 1.f / l1;
#pragma unroll
    for (int qh = 0; qh < 2; qh++) {
        f32x16& a = qh ? o10 : o00;
        f32x16& bq_ = qh ? o11 : o01;
        float inv = qh ? inv1 : inv0;
        int q = qh * 32 + lq;
        int sw = (q & 7) << 4;
#pragma unroll
        for (int g = 0; g < 4; g++) {
            bf16x4 p0, p1;
#pragma unroll
            for (int j = 0; j < 4; j++) {
                p0[j] = (bf16)(a[g * 4 + j] * inv);
                p1[j] = (bf16)(bq_[g * 4 + j] * inv);
            }
            int colb = g * 16 + hi * 8;
            *(bf16x4*)((char*)Ep + q * 128 + (colb ^ sw)) = p0;
            *(bf16x4*)((char*)Ep + q * 128 + ((64 + colb) ^ sw)) = p1;
        }
    }
    const int c = lane & 15, g = lane >> 4;
#pragma unroll
    for (int mt = 0; mt < 4; mt++) {
#pragma unroll
        for (int s = 0; s < 2; s++) {
            int row = mt * 16 + c;
            int colb = (s * 64 + g * 16) ^ ((row & 7) << 4);
            bf16x8 val = *(const bf16x8*)((const char*)Ep + row * 128 + colb);
            size_t mtg = (size_t)((b * SEQ + qw) >> 4) + mt;
            *(bf16x8*)(ctxp + ((mtg * 24 + h * 2 + s) * 64 + lane) * 8) = val;
        }
    }
}

// ============ output projection + bias + residual (packed operands) ============
__global__ __launch_bounds__(256, 2) void oproj_gemm(
    const bf16* __restrict__ Cp, const bf16* __restrict__ Wo, const float* __restrict__ bo,
    const float* __restrict__ hidden, float* __restrict__ y)
{
    int lane = threadIdx.x & 63;
    int wid  = threadIdx.x >> 6;
    int wm = wid >> 1, wn = wid & 1;
    int g = lane >> 4, c = lane & 15;
    int m0 = blockIdx.y * 128 + wm * 64;
    int n0 = blockIdx.x * 128 + wn * 64;

    f32x4 acc[4][4] = {};
    const bf16* Ap = Cp + ((size_t)(m0 >> 4) * 24) * 512 + (size_t)lane * 8;
    const bf16* Bp = Wo + ((size_t)(n0 >> 4) * 24) * 512 + (size_t)lane * 8;

    for (int ks = 0; ks < 24; ks++) {
        bf16x8 a[4], b[4];
#pragma unroll
        for (int i = 0; i < 4; i++) {
            a[i] = *(const bf16x8*)(Ap + ((size_t)i * 24 + ks) * 512);
            b[i] = *(const bf16x8*)(Bp + ((size_t)i * 24 + ks) * 512);
        }
#pragma unroll
        for (int mi = 0; mi < 4; mi++)
#pragma unroll
            for (int ni = 0; ni < 4; ni++)
                acc[mi][ni] = __builtin_amdgcn_mfma_f32_16x16x32_bf16(a[mi], b[ni], acc[mi][ni], 0, 0, 0);
    }

#pragma unroll
    for (int ni = 0; ni < 4; ni++) {
        int n = n0 + ni * 16 + c;
        float bval = bo[n];
#pragma unroll
        for (int mi = 0; mi < 4; mi++) {
#pragma unroll
            for (int j = 0; j < 4; j++) {
                int m = m0 + mi * 16 + g * 4 + j;
                size_t idx = (size_t)m * HID + n;
                y[idx] = acc[mi][ni][j] + bval + hidden[idx];
            }
        }
    }
}

// ============ LayerNorm ============
__global__ __launch_bounds__(256) void ln_kernel(
    const float* __restrict__ y, const float* __restrict__ gam,
    const float* __restrict__ bet, float* __restrict__ out)
{
    int row = blockIdx.x * 4 + (threadIdx.x >> 6);
    int lane = threadIdx.x & 63;
    const float* yr = y + (size_t)row * HID;

    float4 v[3];
#pragma unroll
    for (int i = 0; i < 3; i++)
        v[i] = reinterpret_cast<const float4*>(yr)[lane + i * 64];

    float s = 0.f;
#pragma unroll
    for (int i = 0; i < 3; i++) s += v[i].x + v[i].y + v[i].z + v[i].w;
#pragma unroll
    for (int msk = 1; msk < 64; msk <<= 1) s += __shfl_xor(s, msk, 64);
    float mean = s * (1.f / 768.f);

    float q = 0.f;
#pragma unroll
    for (int i = 0; i < 3; i++) {
        float dx = v[i].x - mean, dy = v[i].y - mean, dz = v[i].z - mean, dw = v[i].w - mean;
        q += dx * dx + dy * dy + dz * dz + dw * dw;
    }
#pragma unroll
    for (int msk = 1; msk < 64; msk <<= 1) q += __shfl_xor(q, msk, 64);
    float rstd = rsqrtf(q * (1.f / 768.f) + 1e-12f);

    float* outr = out + (size_t)row * HID;
#pragma unroll
    for (int i = 0; i < 3; i++) {
        float4 gg = reinterpret_cast<const float4*>(gam)[lane + i * 64];
        float4 bb = reinterpret_cast<const float4*>(bet)[lane + i * 64];
        float4 o;
        o.x = (v[i].x - mean) * rstd * gg.x + bb.x;
        o.y = (v[i].y - mean) * rstd * gg.y + bb.y;
        o.z = (v[i].z - mean) * rstd * gg.z + bb.z;
        o.w = (v[i].w - mean) * rstd * gg.w + bb.w;
        reinterpret_cast<float4*>(outr)[lane + i * 64] = o;
    }
}

extern "C" void kernel_launch(void* const* d_in, const int* in_sizes, int n_in,
                              void* d_out, int out_size, void* d_ws, size_t ws_size,
                              hipStream_t stream) {
    const float* hidden = (const float*)d_in[0];
    const float* mask   = (const float*)d_in[1];
    const float* q_w = (const float*)d_in[2];
    const float* q_b = (const float*)d_in[3];
    const float* k_w = (const float*)d_in[4];
    const float* k_b = (const float*)d_in[5];
    const float* v_w = (const float*)d_in[6];
    const float* v_b = (const float*)d_in[7];
    const float* o_w = (const float*)d_in[8];
    const float* o_b = (const float*)d_in[9];
    const float* ln_g = (const float*)d_in[10];
    const float* ln_b = (const float*)d_in[11];
    float* out = (float*)d_out;

    const size_t SZ_X = (size_t)MTOT * HID;
    const size_t SZ_W = (size_t)HID * HID;

    char* ws = (char*)d_ws;
    size_t XB_OFF = 0;
    size_t W_OFF  = XB_OFF + SZ_X * 2;
    size_t QH_OFF = W_OFF + 4 * SZ_W * 2;
    size_t KH_OFF = QH_OFF + SZ_X * 2;
    size_t VT_OFF = KH_OFF + SZ_X * 2;

    bf16* Xp  = (bf16*)(ws + XB_OFF);
    bf16* Wqp = (bf16*)(ws + W_OFF);
    bf16* Wkp = Wqp + SZ_W;
    bf16* Wvp = Wkp + SZ_W;
    bf16* Wop = Wvp + SZ_W;
    bf16* Qh  = (bf16*)(ws + QH_OFF);
    bf16* Kh  = (bf16*)(ws + KH_OFF);
    bf16* Vt  = (bf16*)(ws + VT_OFF);
    bf16* ctxp = (bf16*)(ws + XB_OFF);   // alias: Xp dead after qkv_gemm
    float* y  = (float*)(ws + QH_OFF);   // alias: Qh/Kh dead after attn

    // fragment-pack inputs
    pack_a<<<dim3(MTOT / 16), 64, 0, stream>>>(hidden, Xp);
    pack_w4<<<dim3(HID / 16, 4), 64, 0, stream>>>(q_w, k_w, v_w, o_w, Wqp, Wkp, Wvp, Wop);

    qkv_gemm<<<dim3(HID / 128, MTOT / 128, 3), 256, 0, stream>>>(
        Xp, Wqp, Wkp, Wvp, q_b, k_b, v_b, Qh, Kh, Vt);

    attn_kernel<<<dim3(NB * NHEAD, SEQ / 64), 128, 0, stream>>>(Qh, Kh, Vt, mask, ctxp);

    oproj_gemm<<<dim3(HID / 128, MTOT / 128), 256, 0, stream>>>(ctxp, Wop, o_b, hidden, y);

    ln_kernel<<<dim3(MTOT / 4), 256, 0, stream>>>(y, ln_g, ln_b, out);
}

// Round 7
// 273.407 us; speedup vs baseline: 2.1268x; 1.0887x over previous
//
#include <hip/hip_runtime.h>

typedef __bf16 bf16;
typedef __bf16 bf16x4 __attribute__((ext_vector_type(4)));
typedef __bf16 bf16x8 __attribute__((ext_vector_type(8)));
typedef float f32x4 __attribute__((ext_vector_type(4)));
typedef float f32x16 __attribute__((ext_vector_type(16)));

#define NB 2
#define SEQ 4096
#define HID 768
#define NHEAD 12
#define HDIM 64
#define MTOT (NB * SEQ)   // 8192
#define LOG2E 1.4426950408889634f

// ============ fragment-pack kernels ============
// A/B-frag layout for mfma_f32_16x16x32_bf16 over a row-major [R][768] fp32 matrix:
// out[((rtile*24 + kstep)*64 + lane)*8 + j] = in[rtile*16 + (lane&15)][kstep*32 + (lane>>4)*8 + j]
__device__ inline void pack_body(const float* __restrict__ in, bf16* __restrict__ out, int rt) {
    __shared__ alignas(16) bf16 T[16 * 264];
    const int lane = threadIdx.x;
    const int c = lane & 15, g = lane >> 4;
    const float4* in4 = (const float4*)in + (size_t)rt * 16 * (HID / 4);
    for (int chunk = 0; chunk < 3; chunk++) {
#pragma unroll
        for (int i = 0; i < 16; i++) {
            float4 v = in4[(size_t)i * (HID / 4) + chunk * 64 + lane];
            bf16x4 o;
            o[0] = (bf16)v.x; o[1] = (bf16)v.y; o[2] = (bf16)v.z; o[3] = (bf16)v.w;
            *(bf16x4*)&T[i * 264 + lane * 4] = o;
        }
        __syncthreads();
#pragma unroll
        for (int s = 0; s < 8; s++) {
            bf16x8 val = *(const bf16x8*)&T[c * 264 + s * 32 + g * 8];
            *(bf16x8*)(out + (((size_t)rt * 24 + chunk * 8 + s) * 64 + lane) * 8) = val;
        }
        __syncthreads();
    }
}

__global__ __launch_bounds__(64) void pack_a(const float* __restrict__ in, bf16* __restrict__ out) {
    pack_body(in, out, blockIdx.x);
}

__global__ __launch_bounds__(64) void pack_w4(
    const float* __restrict__ w0, const float* __restrict__ w1,
    const float* __restrict__ w2, const float* __restrict__ w3,
    bf16* __restrict__ o0, bf16* __restrict__ o1, bf16* __restrict__ o2, bf16* __restrict__ o3) {
    int y = blockIdx.y;
    const float* in = (y == 0) ? w0 : (y == 1) ? w1 : (y == 2) ? w2 : w3;
    bf16* out = (y == 0) ? o0 : (y == 1) ? o1 : (y == 2) ? o2 : o3;
    pack_body(in, out, blockIdx.x);
}

// ============ fused QKV projection GEMM (packed operands) ============
__global__ __launch_bounds__(256, 2) void qkv_gemm(
    const bf16* __restrict__ Xp,
    const bf16* __restrict__ Wq, const bf16* __restrict__ Wk, const bf16* __restrict__ Wv,
    const float* __restrict__ bq, const float* __restrict__ bk, const float* __restrict__ bv,
    bf16* __restrict__ Qh, bf16* __restrict__ Kh, bf16* __restrict__ Vt)
{
    int z = blockIdx.z;
    const bf16* W = (z == 0) ? Wq : (z == 1) ? Wk : Wv;
    const float* bias = (z == 0) ? bq : (z == 1) ? bk : bv;

    int lane = threadIdx.x & 63;
    int wid  = threadIdx.x >> 6;
    int wm = wid >> 1, wn = wid & 1;
    int g = lane >> 4, c = lane & 15;
    int m0 = blockIdx.y * 128 + wm * 64;
    int n0 = blockIdx.x * 128 + wn * 64;

    f32x4 acc[4][4] = {};
    const bf16* Ap = Xp + ((size_t)(m0 >> 4) * 24) * 512 + (size_t)lane * 8;
    const bf16* Bp = W  + ((size_t)(n0 >> 4) * 24) * 512 + (size_t)lane * 8;

    for (int ks = 0; ks < 24; ks++) {
        bf16x8 a[4], b[4];
#pragma unroll
        for (int i = 0; i < 4; i++) {
            a[i] = *(const bf16x8*)(Ap + ((size_t)i * 24 + ks) * 512);
            b[i] = *(const bf16x8*)(Bp + ((size_t)i * 24 + ks) * 512);
        }
#pragma unroll
        for (int mi = 0; mi < 4; mi++)
#pragma unroll
            for (int ni = 0; ni < 4; ni++)
                acc[mi][ni] = __builtin_amdgcn_mfma_f32_16x16x32_bf16(a[mi], b[ni], acc[mi][ni], 0, 0, 0);
    }

#pragma unroll
    for (int ni = 0; ni < 4; ni++) {
        int n = n0 + ni * 16 + c;
        float bval = bias[n];
        int h = n >> 6, d = n & 63;
#pragma unroll
        for (int mi = 0; mi < 4; mi++) {
#pragma unroll
            for (int j = 0; j < 4; j++) {
                int m = m0 + mi * 16 + g * 4 + j;
                float val = acc[mi][ni][j] + bval;
                int bb = m >> 12, s = m & 4095;
                size_t bhb = (size_t)(bb * NHEAD + h) * SEQ * HDIM;
                if (z == 0) {
                    val *= 0.125f * LOG2E;
                    Qh[bhb + (size_t)s * HDIM + d] = (bf16)val;
                } else if (z == 1) {
                    int fragidx = (((s >> 5) & 1) << 2) | (d >> 4);
                    int lane2 = (s & 31) | (((d >> 3) & 1) << 5);
                    Kh[bhb + (size_t)(s >> 6) * 4096 + fragidx * 512 + lane2 * 8 + (d & 7)] = (bf16)val;
                } else {
                    int fragidx = ((d >> 5) << 2) | ((s >> 4) & 3);
                    int lane2 = (d & 31) | (((s >> 3) & 1) << 5);
                    Vt[bhb + (size_t)(s >> 6) * 4096 + fragidx * 512 + lane2 * 8 + (s & 7)] = (bf16)val;
                }
            }
        }
    }
}

// ============ softmax helpers ============
__device__ inline float xhalf_max(float x) {
    float a_ = x, b_ = x;
    asm("v_permlane32_swap_b32 %0, %1" : "+v"(a_), "+v"(b_));
    return fmaxf(a_, b_);
}
__device__ inline float xhalf_sum(float x) {
    float a_ = x, b_ = x;
    asm("v_permlane32_swap_b32 %0, %1" : "+v"(a_), "+v"(b_));
    return a_ + b_;
}

// online softmax for one 32k x 32q score block (s: 16 vals/lane)
__device__ inline void smax16(f32x16& s, float& m, float& l, f32x16& o0, f32x16& o1) {
    float r[8];
#pragma unroll
    for (int i = 0; i < 8; i++) r[i] = fmaxf(s[i], s[i + 8]);
#pragma unroll
    for (int st = 4; st; st >>= 1)
#pragma unroll
        for (int i = 0; i < st; i++) r[i] = fmaxf(r[i], r[i + st]);
    float t = xhalf_max(r[0]);
    if (__any(t > m + 8.f)) {          // defer-max (T13)
        float mn = fmaxf(m, t);
        float al = __builtin_amdgcn_exp2f(m - mn);
        m = mn; l *= al;
#pragma unroll
        for (int i = 0; i < 16; i++) { o0[i] *= al; o1[i] *= al; }
    }
#pragma unroll
    for (int i = 0; i < 16; i++) s[i] = __builtin_amdgcn_exp2f(s[i] - m);
    float q[8];
#pragma unroll
    for (int i = 0; i < 8; i++) q[i] = s[i] + s[i + 8];
#pragma unroll
    for (int st = 4; st; st >>= 1)
#pragma unroll
        for (int i = 0; i < st; i++) q[i] += q[i + st];
    l += xhalf_sum(q[0]);
}

// P (f32 D-layout, one 32k block) -> 2 bf16 B-frags (k 0..15, 16..31)
__device__ inline void pconv16(const f32x16& sc, bf16x8* pa) {
    unsigned u[8];
#pragma unroll
    for (int i = 0; i < 8; i++) {
        union { bf16 hh[2]; unsigned uu; } x;
        x.hh[0] = (bf16)sc[i * 2];
        x.hh[1] = (bf16)sc[i * 2 + 1];
        u[i] = x.uu;
    }
    asm("v_permlane32_swap_b32 %0, %1" : "+v"(u[0]), "+v"(u[2]));
    asm("v_permlane32_swap_b32 %0, %1" : "+v"(u[1]), "+v"(u[3]));
    asm("v_permlane32_swap_b32 %0, %1" : "+v"(u[4]), "+v"(u[6]));
    asm("v_permlane32_swap_b32 %0, %1" : "+v"(u[5]), "+v"(u[7]));
    union { unsigned uu[4]; bf16x8 v; } f0, f1;
    f0.uu[0] = u[0]; f0.uu[1] = u[1]; f0.uu[2] = u[2]; f0.uu[3] = u[3];
    f1.uu[0] = u[4]; f1.uu[1] = u[5]; f1.uu[2] = u[6]; f1.uu[3] = u[7];
    pa[0] = f0.v;
    pa[1] = f1.v;
}

// ============ flash attention: 4 waves = 2 q-groups x split-K-2, 32q/wave, 32k tiles ============
// grid (NB*NHEAD, SEQ/64), block 256. Small per-wave state (~120 regs) -> 4 waves/SIMD.
// XCD = bh%8 -> 3 heads/XCD, K/V L2-resident. All K/V loads lane-contiguous (frag-packed).
__global__ __launch_bounds__(256, 4) void attn_kernel(
    const bf16* __restrict__ Qh, const bf16* __restrict__ Kh, const bf16* __restrict__ Vt,
    const float* __restrict__ mask, bf16* __restrict__ ctxp)
{
    __shared__ float Sm[2][2048];              // 16KB: kp1 o-state per q-group
    __shared__ float Sml[2][128];              // 1KB:  kp1 m/l
    __shared__ alignas(16) bf16 Ep[2][2048];   // 8KB:  epilogue coalesce

    const int lane = threadIdx.x & 63;
    const int wid = threadIdx.x >> 6;
    const int qg = wid >> 1;                   // q-group 0/1
    const int kp = wid & 1;                    // k parity
    const int lq = lane & 31;
    const int hi = lane >> 5;
    const int bh = blockIdx.x;
    const int b = bh / NHEAD, h = bh % NHEAD;
    const size_t base = (size_t)bh * SEQ * HDIM;
    const int qw = blockIdx.y * 64 + qg * 32;  // this wave's 32 q-rows

    // Q B-frags (pre-scaled): lane holds Q[qw+lq][dc*16 + hi*8 + j]
    bf16x8 qf[4];
#pragma unroll
    for (int dc = 0; dc < 4; dc++)
        qf[dc] = *(const bf16x8*)(Qh + base + (size_t)(qw + lq) * HDIM + dc * 16 + hi * 8);

    const float* maskb = mask + b * SEQ;
    const bf16* kfrag = Kh + base + (size_t)lane * 8;
    const bf16* vfrag = Vt + base + (size_t)lane * 8;

    float m = -3e38f, l = 0.f;
    f32x16 o0 = {}, o1 = {};                   // o[dhalf]: O^T[d][q]

    for (int t = 0; t < SEQ / 64; t++) {
        const int kt = 2 * t + kp;             // 32-row k tile index
        const size_t tb = (size_t)(kt >> 1) * 4096;
        const int khalf = kt & 1;

        bf16x8 kf[4];
#pragma unroll
        for (int dc = 0; dc < 4; dc++)
            kf[dc] = *(const bf16x8*)(kfrag + tb + (khalf * 4 + dc) * 512);

        // QK^T: S[k][q] for 32 k-rows
        f32x16 s = {};
#pragma unroll
        for (int dc = 0; dc < 4; dc++)
            s = __builtin_amdgcn_mfma_f32_32x32x16_bf16(kf[dc], qf[dc], s, 0, 0, 0);

        // K regs dead -> V loads issue now, latency hides under softmax
        bf16x8 vf[4];
        vf[0] = *(const bf16x8*)(vfrag + tb + (khalf * 2 + 0) * 512);
        vf[1] = *(const bf16x8*)(vfrag + tb + (khalf * 2 + 1) * 512);
        vf[2] = *(const bf16x8*)(vfrag + tb + (4 + khalf * 2 + 0) * 512);
        vf[3] = *(const bf16x8*)(vfrag + tb + (4 + khalf * 2 + 1) * 512);

        // mask add (exp2 domain)
        const float* mrow = maskb + kt * 32 + hi * 4;
#pragma unroll
        for (int g = 0; g < 4; g++) {
            f32x4 mk = *(const f32x4*)(mrow + g * 8);
#pragma unroll
            for (int j = 0; j < 4; j++)
                s[g * 4 + j] += mk[j] * LOG2E;
        }

        smax16(s, m, l, o0, o1);
        bf16x8 pa[2];
        pconv16(s, pa);

        // PV: O^T[d][q] += V^T P^T
        o0 = __builtin_amdgcn_mfma_f32_32x32x16_bf16(vf[0], pa[0], o0, 0, 0, 0);
        o0 = __builtin_amdgcn_mfma_f32_32x32x16_bf16(vf[1], pa[1], o0, 0, 0, 0);
        o1 = __builtin_amdgcn_mfma_f32_32x32x16_bf16(vf[2], pa[0], o1, 0, 0, 0);
        o1 = __builtin_amdgcn_mfma_f32_32x32x16_bf16(vf[3], pa[1], o1, 0, 0, 0);
    }

    // ---- split-K merge: kp1 parks state, kp0 combines ----
    if (kp == 1) {
#pragma unroll
        for (int i = 0; i < 16; i++) {
            Sm[qg][i * 64 + lane]        = o0[i];
            Sm[qg][(16 + i) * 64 + lane] = o1[i];
        }
        Sml[qg][lane] = m; Sml[qg][64 + lane] = l;
    }
    __syncthreads();
    if (kp == 1) return;

    {
        float mB = Sml[qg][lane], lB = Sml[qg][64 + lane];
        float mm = fmaxf(m, mB);
        float a = __builtin_amdgcn_exp2f(m - mm);
        float bb_ = __builtin_amdgcn_exp2f(mB - mm);
        l = l * a + lB * bb_;
#pragma unroll
        for (int i = 0; i < 16; i++) {
            o0[i] = o0[i] * a + Sm[qg][i * 64 + lane] * bb_;
            o1[i] = o1[i] * a + Sm[qg][(16 + i) * 64 + lane] * bb_;
        }
    }

    // ---- epilogue: O/l -> Ep (swizzled) -> ctx FRAG-PACKED for oproj ----
    float inv = 1.f / l;
    bf16* ep = Ep[qg];
    const int sw = (lq & 7) << 4;
#pragma unroll
    for (int g = 0; g < 4; g++) {
        bf16x4 p0, p1;
#pragma unroll
        for (int j = 0; j < 4; j++) {
            p0[j] = (bf16)(o0[g * 4 + j] * inv);
            p1[j] = (bf16)(o1[g * 4 + j] * inv);
        }
        int colb = g * 16 + hi * 8;
        *(bf16x4*)((char*)ep + lq * 128 + (colb ^ sw)) = p0;
        *(bf16x4*)((char*)ep + lq * 128 + ((64 + colb) ^ sw)) = p1;
    }
    const int c = lane & 15, gg = lane >> 4;
#pragma unroll
    for (int mt = 0; mt < 2; mt++) {
#pragma unroll
        for (int s2 = 0; s2 < 2; s2++) {
            int row = mt * 16 + c;
            int colb = (s2 * 64 + gg * 16) ^ ((row & 7) << 4);
            bf16x8 val = *(const bf16x8*)((const char*)ep + row * 128 + colb);
            size_t mtg = (size_t)((b * SEQ + qw) >> 4) + mt;
            *(bf16x8*)(ctxp + ((mtg * 24 + h * 2 + s2) * 64 + lane) * 8) = val;
        }
    }
}

// ============ output projection + bias + residual (packed operands) ============
__global__ __launch_bounds__(256, 2) void oproj_gemm(
    const bf16* __restrict__ Cp, const bf16* __restrict__ Wo, const float* __restrict__ bo,
    const float* __restrict__ hidden, float* __restrict__ y)
{
    int lane = threadIdx.x & 63;
    int wid  = threadIdx.x >> 6;
    int wm = wid >> 1, wn = wid & 1;
    int g = lane >> 4, c = lane & 15;
    int m0 = blockIdx.y * 128 + wm * 64;
    int n0 = blockIdx.x * 128 + wn * 64;

    f32x4 acc[4][4] = {};
    const bf16* Ap = Cp + ((size_t)(m0 >> 4) * 24) * 512 + (size_t)lane * 8;
    const bf16* Bp = Wo + ((size_t)(n0 >> 4) * 24) * 512 + (size_t)lane * 8;

    for (int ks = 0; ks < 24; ks++) {
        bf16x8 a[4], b[4];
#pragma unroll
        for (int i = 0; i < 4; i++) {
            a[i] = *(const bf16x8*)(Ap + ((size_t)i * 24 + ks) * 512);
            b[i] = *(const bf16x8*)(Bp + ((size_t)i * 24 + ks) * 512);
        }
#pragma unroll
        for (int mi = 0; mi < 4; mi++)
#pragma unroll
            for (int ni = 0; ni < 4; ni++)
                acc[mi][ni] = __builtin_amdgcn_mfma_f32_16x16x32_bf16(a[mi], b[ni], acc[mi][ni], 0, 0, 0);
    }

#pragma unroll
    for (int ni = 0; ni < 4; ni++) {
        int n = n0 + ni * 16 + c;
        float bval = bo[n];
#pragma unroll
        for (int mi = 0; mi < 4; mi++) {
#pragma unroll
            for (int j = 0; j < 4; j++) {
                int m = m0 + mi * 16 + g * 4 + j;
                size_t idx = (size_t)m * HID + n;
                y[idx] = acc[mi][ni][j] + bval + hidden[idx];
            }
        }
    }
}

// ============ LayerNorm ============
__global__ __launch_bounds__(256) void ln_kernel(
    const float* __restrict__ y, const float* __restrict__ gam,
    const float* __restrict__ bet, float* __restrict__ out)
{
    int row = blockIdx.x * 4 + (threadIdx.x >> 6);
    int lane = threadIdx.x & 63;
    const float* yr = y + (size_t)row * HID;

    float4 v[3];
#pragma unroll
    for (int i = 0; i < 3; i++)
        v[i] = reinterpret_cast<const float4*>(yr)[lane + i * 64];

    float s = 0.f;
#pragma unroll
    for (int i = 0; i < 3; i++) s += v[i].x + v[i].y + v[i].z + v[i].w;
#pragma unroll
    for (int msk = 1; msk < 64; msk <<= 1) s += __shfl_xor(s, msk, 64);
    float mean = s * (1.f / 768.f);

    float q = 0.f;
#pragma unroll
    for (int i = 0; i < 3; i++) {
        float dx = v[i].x - mean, dy = v[i].y - mean, dz = v[i].z - mean, dw = v[i].w - mean;
        q += dx * dx + dy * dy + dz * dz + dw * dw;
    }
#pragma unroll
    for (int msk = 1; msk < 64; msk <<= 1) q += __shfl_xor(q, msk, 64);
    float rstd = rsqrtf(q * (1.f / 768.f) + 1e-12f);

    float* outr = out + (size_t)row * HID;
#pragma unroll
    for (int i = 0; i < 3; i++) {
        float4 gg = reinterpret_cast<const float4*>(gam)[lane + i * 64];
        float4 bb = reinterpret_cast<const float4*>(bet)[lane + i * 64];
        float4 o;
        o.x = (v[i].x - mean) * rstd * gg.x + bb.x;
        o.y = (v[i].y - mean) * rstd * gg.y + bb.y;
        o.z = (v[i].z - mean) * rstd * gg.z + bb.z;
        o.w = (v[i].w - mean) * rstd * gg.w + bb.w;
        reinterpret_cast<float4*>(outr)[lane + i * 64] = o;
    }
}

extern "C" void kernel_launch(void* const* d_in, const int* in_sizes, int n_in,
                              void* d_out, int out_size, void* d_ws, size_t ws_size,
                              hipStream_t stream) {
    const float* hidden = (const float*)d_in[0];
    const float* mask   = (const float*)d_in[1];
    const float* q_w = (const float*)d_in[2];
    const float* q_b = (const float*)d_in[3];
    const float* k_w = (const float*)d_in[4];
    const float* k_b = (const float*)d_in[5];
    const float* v_w = (const float*)d_in[6];
    const float* v_b = (const float*)d_in[7];
    const float* o_w = (const float*)d_in[8];
    const float* o_b = (const float*)d_in[9];
    const float* ln_g = (const float*)d_in[10];
    const float* ln_b = (const float*)d_in[11];
    float* out = (float*)d_out;

    const size_t SZ_X = (size_t)MTOT * HID;
    const size_t SZ_W = (size_t)HID * HID;

    char* ws = (char*)d_ws;
    size_t XB_OFF = 0;
    size_t W_OFF  = XB_OFF + SZ_X * 2;
    size_t QH_OFF = W_OFF + 4 * SZ_W * 2;
    size_t KH_OFF = QH_OFF + SZ_X * 2;
    size_t VT_OFF = KH_OFF + SZ_X * 2;

    bf16* Xp  = (bf16*)(ws + XB_OFF);
    bf16* Wqp = (bf16*)(ws + W_OFF);
    bf16* Wkp = Wqp + SZ_W;
    bf16* Wvp = Wkp + SZ_W;
    bf16* Wop = Wvp + SZ_W;
    bf16* Qh  = (bf16*)(ws + QH_OFF);
    bf16* Kh  = (bf16*)(ws + KH_OFF);
    bf16* Vt  = (bf16*)(ws + VT_OFF);
    bf16* ctxp = (bf16*)(ws + XB_OFF);   // alias: Xp dead after qkv_gemm
    float* y  = (float*)(ws + QH_OFF);   // alias: Qh/Kh dead after attn

    pack_a<<<dim3(MTOT / 16), 64, 0, stream>>>(hidden, Xp);
    pack_w4<<<dim3(HID / 16, 4), 64, 0, stream>>>(q_w, k_w, v_w, o_w, Wqp, Wkp, Wvp, Wop);

    qkv_gemm<<<dim3(HID / 128, MTOT / 128, 3), 256, 0, stream>>>(
        Xp, Wqp, Wkp, Wvp, q_b, k_b, v_b, Qh, Kh, Vt);

    // 4 waves/block: 2 q-groups x split-K-2, 32q/wave, small reg state -> 4 waves/SIMD
    attn_kernel<<<dim3(NB * NHEAD, SEQ / 64), 256, 0, stream>>>(Qh, Kh, Vt, mask, ctxp);

    oproj_gemm<<<dim3(HID / 128, MTOT / 128), 256, 0, stream>>>(ctxp, Wop, o_b, hidden, y);

    ln_kernel<<<dim3(MTOT / 4), 256, 0, stream>>>(y, ln_g, ln_b, out);
}